// Round 14
// baseline (213.717 us; speedup 1.0000x reference)
//
#include <hip/hip_runtime.h>
#include <hip/hip_fp16.h>

typedef unsigned int u32;
typedef unsigned short u16;

#define NIMG 16
#define HH 512
#define WW 512
#define HWSZ (HH*WW)
#define TOPN 2621u
#define TIE_CAP 12288
#define GR 40

// ---------- f16 packing helpers ----------
static __device__ inline u16 f2h(float v){ __half h=__float2half_rn(v); return *reinterpret_cast<u16*>(&h); }
static __device__ inline float h2f(u16 v){ __half h=*reinterpret_cast<__half*>(&v); return __half2float(h); }
static __device__ inline uint2 pack_h4(float4 S){
  __half2 lo = __floats2half2_rn(S.x, S.y);
  __half2 hi = __floats2half2_rn(S.z, S.w);
  uint2 r;
  r.x = *reinterpret_cast<unsigned int*>(&lo);
  r.y = *reinterpret_cast<unsigned int*>(&hi);
  return r;
}
static __device__ inline float4 unpack_h4(uint2 v){
  __half2 lo = *reinterpret_cast<__half2*>(&v.x);
  __half2 hi = *reinterpret_cast<__half2*>(&v.y);
  float2 A = __half22float2(lo), B = __half22float2(hi);
  return make_float4(A.x, A.y, B.x, B.y);
}
static __device__ inline u32 pack_h2(float a, float b){
  __half2 h = __floats2half2_rn(a, b);
  return *reinterpret_cast<unsigned int*>(&h);
}
static __device__ inline float2 unpack_h2(u32 v){
  __half2 h = *reinterpret_cast<__half2*>(&v);
  return __half22float2(h);
}

// ---------------- prep: x -> img16(3 planes), guid16, row-min f32 (dark path), zero state ----------------
__global__ void k_prep(const float* __restrict__ x, u16* __restrict__ imgh,
                       u16* __restrict__ guidh, float* __restrict__ rowm,
                       u32* __restrict__ state, int zwords){
  __shared__ float s[WW+14];
  int row = blockIdx.x; int n = row>>9; int y = row&511; int t = threadIdx.x;
  int zi = row*512 + t;
  if(zi < zwords) state[zi] = 0;
  const float* xb = x + (size_t)n*3*HWSZ + (size_t)y*WW + t;
  float x0=xb[0], x1=xb[HWSZ], x2=xb[2*HWSZ];
  float i0=(x0+1.f)*0.5f, i1=(x1+1.f)*0.5f, i2=(x2+1.f)*0.5f;
  size_t po = (size_t)n*3*HWSZ + (size_t)y*WW + t;
  imgh[po] = f2h(i0); imgh[po+HWSZ] = f2h(i1); imgh[po+2*HWSZ] = f2h(i2);
  float g = (0.2989f*x0 + 0.587f*x1 + 0.114f*x2 + 1.f)*0.5f;   // exact reference form
  size_t qo = (size_t)n*HWSZ + (size_t)y*WW + t;
  guidh[qo] = f2h(g);
  float m = fminf(i0, fminf(i1, i2));
  s[t+7] = m;
  if(t < 7) s[t] = 1.0f;
  if(t >= WW-7) s[t+14] = 1.0f;
  __syncthreads();
  float v = s[t];
  #pragma unroll
  for(int d=1; d<15; ++d) v = fminf(v, s[t+d]);
  rowm[qo] = v;
}

// ---------------- 15-tap col min f32 (dark) ----------------
__global__ void k_colmin_dark(const float* __restrict__ in, float* __restrict__ out){
  int x4 = threadIdx.x;            // 128 threads = 512 floats
  int y = blockIdx.x;
  int n = blockIdx.y;
  const float4* base = (const float4*)(in + (size_t)n*HWSZ);
  float4 v = {3.0e38f,3.0e38f,3.0e38f,3.0e38f};
  #pragma unroll
  for(int d=-7; d<=7; ++d){
    int yy = y + d;
    if(yy >= 0 && yy < HH){
      float4 tp = base[(size_t)yy*(WW/4) + x4];
      v.x=fminf(v.x,tp.x); v.y=fminf(v.y,tp.y); v.z=fminf(v.z,tp.z); v.w=fminf(v.w,tp.w);
    } else {
      v.x=fminf(v.x,1.f); v.y=fminf(v.y,1.f); v.z=fminf(v.z,1.f); v.w=fminf(v.w,1.f);
    }
  }
  ((float4*)(out + (size_t)n*HWSZ))[(size_t)y*(WW/4) + x4] = v;
}

__device__ inline u32 block_scan_incl(u32 v, int t, u32* wsum){
  #pragma unroll
  for(int d=1; d<64; d<<=1){
    u32 u = __shfl_up(v, d);
    if((t & 63) >= d) v += u;
  }
  if((t & 63) == 63) wsum[t >> 6] = v;
  __syncthreads();
  u32 carry = 0;
  for(int w=0; w < (t >> 6); ++w) carry += wsum[w];
  return v + carry;
}

// ---------------- selection: histogram bits [22:10] ----------------
__global__ void k_hist1(const float* __restrict__ dark, u32* __restrict__ hist1){
  __shared__ u32 h[8192];
  int n = blockIdx.x, part = blockIdx.y, t = threadIdx.x;  // 1024 threads
  for(int i=t; i<8192; i+=1024) h[i] = 0;
  __syncthreads();
  const u32* d = (const u32*)(dark + (size_t)n*HWSZ);
  int per = HWSZ/8, i0 = part*per;
  for(int i=i0+t; i<i0+per; i+=1024){
    u32 key = d[i];
    int b = (int)(key >> 10) - 0xFC000;
    b = max(0, min(8191, b));
    atomicAdd(&h[b], 1u);
  }
  __syncthreads();
  u32* gh = hist1 + n*8192;
  for(int i=t; i<8192; i+=1024) if(h[i]) atomicAdd(&gh[i], h[i]);
}

// ------- sel4 with csel1 prologue; sums over bins > bin_hi, ties = whole bin_hi bin -------
__global__ void k_sel4(const float* __restrict__ dark, const float* __restrict__ x,
                       const u32* __restrict__ hist1, u32* __restrict__ st,
                       float* __restrict__ sums, u32* __restrict__ ties_i,
                       u32* __restrict__ ties_v){
  __shared__ u32 wsum[16];
  __shared__ u32 bc[1];
  __shared__ float red[1024];
  int n = blockIdx.x, part = blockIdx.y, t = threadIdx.x;   // 1024 threads
  // csel1 prologue: every block redundantly scans hist1 (built in a prior dispatch)
  const u32* hh = hist1 + n*8192;
  u32 loc[8]; u32 ps = 0;
  #pragma unroll
  for(int k=0; k<8; ++k){
    loc[k] = hh[8191 - (t*8 + k)];
    ps += loc[k];
  }
  u32 incl = block_scan_incl(ps, t, wsum);
  u32 excl = incl - ps;
  if(excl < TOPN && incl >= TOPN){
    u32 cum = excl;
    #pragma unroll
    for(int k=0; k<8; ++k){
      if(cum + loc[k] >= TOPN){
        bc[0] = (u32)(8191 - (t*8+k));
        st[n*16+6] = TOPN - cum;      // k_need (racing identical writes: benign)
        break;
      }
      cum += loc[k];
    }
  }
  __syncthreads();
  int bin_hi = (int)bc[0];
  const u32* d = (const u32*)(dark + (size_t)n*HWSZ);
  const float* xb = x + (size_t)n*3*HWSZ;
  float a0=0.f, a1=0.f, a2=0.f;
  int per = HWSZ/8, i0 = part*per;
  for(int i=i0+t; i<i0+per; i+=1024){
    u32 key = d[i];
    int b = (int)(key >> 10) - 0xFC000;
    b = max(0, min(8191, b));
    if(b > bin_hi){
      a0 += xb[i]; a1 += xb[i+HWSZ]; a2 += xb[i+2*HWSZ];
    } else if(b == bin_hi){
      u32 pos = atomicAdd(&st[n*16+7], 1u);
      if(pos < TIE_CAP){ ties_i[n*TIE_CAP + pos] = (u32)i; ties_v[n*TIE_CAP + pos] = key; }
    }
  }
  red[t]=a0; __syncthreads();
  for(int s=512;s>0;s>>=1){ if(t<s) red[t]+=red[t+s]; __syncthreads(); }
  if(t==0) atomicAdd(&sums[n*8+0], red[0]);
  __syncthreads();
  red[t]=a1; __syncthreads();
  for(int s=512;s>0;s>>=1){ if(t<s) red[t]+=red[t+s]; __syncthreads(); }
  if(t==0) atomicAdd(&sums[n*8+1], red[0]);
  __syncthreads();
  red[t]=a2; __syncthreads();
  for(int s=512;s>0;s>>=1){ if(t<s) red[t]+=red[t+s]; __syncthreads(); }
  if(t==0) atomicAdd(&sums[n*8+2], red[0]);
}

// ---- sel5: exact top-k among bin ties: low-10-bit value search, then index cutoff ----
__global__ void k_sel5(const float* __restrict__ x, const u32* __restrict__ st,
                       const float* __restrict__ sums, const u32* __restrict__ ties_i,
                       const u32* __restrict__ ties_v, float* __restrict__ A){
  __shared__ u32 tl[TIE_CAP];
  __shared__ u16 kv[TIE_CAP];
  __shared__ u32 redu[1024];
  __shared__ float red[1024];
  __shared__ float fin[3];
  int n = blockIdx.x, t = threadIdx.x;   // 1024
  u32 k_need = st[n*16+6];
  u32 m = st[n*16+7]; if(m > TIE_CAP) m = TIE_CAP;
  const float* xb = x + (size_t)n*3*HWSZ;
  for(u32 e=t; e<m; e+=1024){
    tl[e] = ties_i[n*TIE_CAP + e];
    kv[e] = (u16)(ties_v[n*TIE_CAP + e] & 1023u);   // within one bin only low 10 bits differ
  }
  __syncthreads();
  // phase 1: vstar = k_need-th largest low-bits value, search [0,1023] (no overflow)
  u32 vlo = 0u, vhi = 1023u;
  while(vlo < vhi){
    u32 mid = (vlo + vhi + 1u) >> 1;
    u32 c = 0;
    for(u32 e=t; e<m; e+=1024) c += ((u32)kv[e] >= mid) ? 1u : 0u;
    redu[t] = c; __syncthreads();
    for(int s=512;s>0;s>>=1){ if(t<s) redu[t]+=redu[t+s]; __syncthreads(); }
    u32 total = redu[0]; __syncthreads();
    if(total >= k_need) vlo = mid; else vhi = mid - 1u;
  }
  u32 vstar = vlo;
  // cnt_gt = count(kv > vstar)
  {
    u32 c = 0;
    for(u32 e=t; e<m; e+=1024) c += ((u32)kv[e] > vstar) ? 1u : 0u;
    redu[t] = c; __syncthreads();
    for(int s=512;s>0;s>>=1){ if(t<s) redu[t]+=redu[t+s]; __syncthreads(); }
  }
  u32 cnt_gt = redu[0]; __syncthreads();
  u32 k2 = k_need - cnt_gt;
  // phase 2: smallest C with count(kv==vstar && idx<C) >= k2
  u32 lo = 0, hi = HWSZ;
  while(lo < hi){
    u32 mid = (lo + hi) >> 1;
    u32 c = 0;
    for(u32 e=t; e<m; e+=1024) c += ((u32)kv[e] == vstar && tl[e] < mid) ? 1u : 0u;
    redu[t] = c; __syncthreads();
    for(int s=512;s>0;s>>=1){ if(t<s) redu[t]+=redu[t+s]; __syncthreads(); }
    u32 total = redu[0]; __syncthreads();
    if(total >= k2) hi = mid; else lo = mid + 1;
  }
  u32 C = lo;
  float a0=0.f, a1=0.f, a2=0.f;
  for(u32 e=t; e<m; e+=1024){
    u32 idx = tl[e];
    bool sel = ((u32)kv[e] > vstar) || ((u32)kv[e] == vstar && idx < C);
    if(sel){ a0 += xb[idx]; a1 += xb[idx+HWSZ]; a2 += xb[idx+2*HWSZ]; }
  }
  red[t]=a0; __syncthreads();
  for(int s=512;s>0;s>>=1){ if(t<s) red[t]+=red[t+s]; __syncthreads(); }
  if(t==0) fin[0]=red[0];
  __syncthreads();
  red[t]=a1; __syncthreads();
  for(int s=512;s>0;s>>=1){ if(t<s) red[t]+=red[t+s]; __syncthreads(); }
  if(t==0) fin[1]=red[0];
  __syncthreads();
  red[t]=a2; __syncthreads();
  for(int s=512;s>0;s>>=1){ if(t<s) red[t]+=red[t+s]; __syncthreads(); }
  if(t==0){
    fin[2]=red[0];
    for(int c=0;c<3;++c){
      float tot = sums[n*8+c] + fin[c];
      float Ac = (tot / 2621.0f + 1.0f) * 0.5f;
      A[n*8+c]   = Ac;
      A[n*8+4+c] = 1.0f / Ac;
    }
  }
}

// ---------------- rowmin of img/A (f16 img in, f16 out) ----------------
__global__ void k_rowmin2(const u16* __restrict__ imgh, const float* __restrict__ A,
                          u16* __restrict__ rowm2){
  __shared__ float s[WW+14];
  int row = blockIdx.x; int n = row>>9; int y = row&511; int t = threadIdx.x;
  float ia0=A[n*8+4], ia1=A[n*8+5], ia2=A[n*8+6];
  size_t po = (size_t)n*3*HWSZ + (size_t)y*WW + t;
  float i0=h2f(imgh[po]), i1=h2f(imgh[po+HWSZ]), i2=h2f(imgh[po+2*HWSZ]);
  float m = fminf(i0*ia0, fminf(i1*ia1, i2*ia2));
  s[t+7] = m;
  if(t < 7) s[t] = 1.0f;
  if(t >= WW-7) s[t+14] = 1.0f;
  __syncthreads();
  float v = s[t];
  #pragma unroll
  for(int d=1; d<15; ++d) v = fminf(v, s[t+d]);
  rowm2[(size_t)n*HWSZ + (size_t)y*WW + t] = f2h(v);
}

// -------- hbox4 with fused col-min prologue (reads rowm2) + horizontal box sums + P4 --------
__global__ void k_hbox4(const u16* __restrict__ guidh, const u16* __restrict__ rowm2,
                        uint2* __restrict__ h4, float4* __restrict__ P4){
  __shared__ float4 wsum[8];
  __shared__ float4 pref[WW];
  int b = blockIdx.x; int n = b >> 6; int g = b & 63; int t = threadIdx.x;
  int lane = t & 63, wv = t >> 6;
  // colmin prologue: thread t = column t; rows g*8-7 .. g*8+14 (22), OOB = 1.0
  const u16* rb = rowm2 + (size_t)n*HWSZ;
  float val[22];
  #pragma unroll
  for(int r=0; r<22; ++r){
    int yy = g*8 - 7 + r;
    val[r] = (yy >= 0 && yy < HH) ? h2f(rb[(size_t)yy*WW + t]) : 1.0f;
  }
  float Pv[8];
  #pragma unroll
  for(int j=0; j<8; ++j){
    float mn = val[j];
    #pragma unroll
    for(int d=1; d<15; ++d) mn = fminf(mn, val[j+d]);
    Pv[j] = h2f(f2h(1.0f - 0.95f*mn));   // replicate f16 round-trip exactly
  }
  float4 psum = {0.f,0.f,0.f,0.f};
  for(int j=0; j<8; ++j){
    int y = g*8 + j;
    size_t off = (size_t)n*HWSZ + (size_t)y*WW + t;
    float I = h2f(guidh[off]);
    float P = Pv[j];
    float4 s; s.x = I; s.y = P; s.z = I*P; s.w = I*I;
    #pragma unroll
    for(int d=1; d<64; d<<=1){
      float ux=__shfl_up(s.x,d), uy=__shfl_up(s.y,d), uz=__shfl_up(s.z,d), uw=__shfl_up(s.w,d);
      if(lane >= d){ s.x+=ux; s.y+=uy; s.z+=uz; s.w+=uw; }
    }
    if(lane == 63) wsum[wv] = s;
    __syncthreads();
    float4 c = {0.f,0.f,0.f,0.f};
    for(int w=0; w<wv; ++w){ float4 q=wsum[w]; c.x+=q.x; c.y+=q.y; c.z+=q.z; c.w+=q.w; }
    s.x+=c.x; s.y+=c.y; s.z+=c.z; s.w+=c.w;
    pref[t] = s;
    __syncthreads();
    int hi = min(t+GR, WW-1);
    float4 S = pref[hi];
    if(t >= GR+1){ float4 L = pref[t-GR-1]; S.x-=L.x; S.y-=L.y; S.z-=L.z; S.w-=L.w; }
    uint2 pk = pack_h4(S);
    h4[off] = pk;
    float4 r = unpack_h4(pk);     // accumulate ROUNDED values
    psum.x+=r.x; psum.y+=r.y; psum.z+=r.z; psum.w+=r.w;
    __syncthreads();
  }
  P4[((size_t)n*64 + g)*WW + t] = psum;
}

// -------- horizontal 81-tap box sums of (a,b); 8 rows/block; emits P2 partial --------
__global__ void k_hbox2(const u32* __restrict__ ab, u32* __restrict__ hab,
                        float2* __restrict__ P2){
  __shared__ float2 wsum[8];
  __shared__ float2 pref[WW];
  int b = blockIdx.x; int n = b >> 6; int g = b & 63; int t = threadIdx.x;
  int lane = t & 63, wv = t >> 6;
  float2 psum = {0.f,0.f};
  for(int j=0; j<8; ++j){
    int y = g*8 + j;
    size_t off = (size_t)n*HWSZ + (size_t)y*WW + t;
    float2 s = unpack_h2(ab[off]);
    #pragma unroll
    for(int d=1; d<64; d<<=1){
      float ux=__shfl_up(s.x,d), uy=__shfl_up(s.y,d);
      if(lane >= d){ s.x+=ux; s.y+=uy; }
    }
    if(lane == 63) wsum[wv] = s;
    __syncthreads();
    float2 c = {0.f,0.f};
    for(int w=0; w<wv; ++w){ float2 q=wsum[w]; c.x+=q.x; c.y+=q.y; }
    s.x+=c.x; s.y+=c.y;
    pref[t] = s;
    __syncthreads();
    int hi = min(t+GR, WW-1);
    float2 S = pref[hi];
    if(t >= GR+1){ float2 L = pref[t-GR-1]; S.x-=L.x; S.y-=L.y; }
    u32 pk = pack_h2(S.x, S.y);
    hab[off] = pk;
    float2 r = unpack_h2(pk);
    psum.x+=r.x; psum.y+=r.y;
    __syncthreads();
  }
  P2[((size_t)n*64 + g)*WW + t] = psum;
}

// ---------------- vertical 81-tap running sums (pyramid init, y-chunk 8) -> a,b ----------------
__global__ void k_vbox_ab(const uint2* __restrict__ h4, const float4* __restrict__ P4,
                          u32* __restrict__ ab){
  int xc = blockIdx.x*256 + threadIdx.x;
  int n = blockIdx.z;
  int y0 = blockIdx.y*8;
  const uint2* hb = h4 + (size_t)n*HWSZ;
  const float4* pb = P4 + (size_t)n*64*WW + xc;
  u32* abb = ab + (size_t)n*HWSZ;
  int nx = min(xc+GR, WW-1) - max(xc-GR, 0) + 1;

  int lo = y0-GR; if(lo < 0) lo = 0;
  int hi = y0+GR; if(hi > HH-1) hi = HH-1;
  int g_lo = lo >> 3;
  int g_hi = ((hi+1) >> 3) - 1;
  float s0=0.f, s1=0.f, s2=0.f, s3=0.f;
  #pragma unroll 6
  for(int g=g_lo; g<=g_hi; ++g){
    float4 v = pb[(size_t)g*WW];
    s0+=v.x; s1+=v.y; s2+=v.z; s3+=v.w;
  }
  for(int y=(g_hi+1)*8; y<=hi; ++y){
    float4 v = unpack_h4(hb[(size_t)y*WW + xc]);
    s0+=v.x; s1+=v.y; s2+=v.z; s3+=v.w;
  }

  #pragma unroll
  for(int g=0; g<2; ++g){
    uint2 ad[4], sb[4];
    bool va4[4], vs4[4];
    #pragma unroll
    for(int j=0; j<4; ++j){
      int y = y0 + g*4 + j;
      int ya = y+GR+1, yr = y-GR;
      va4[j] = (ya < HH); vs4[j] = (yr >= 0);
      ad[j] = va4[j] ? hb[(size_t)ya*WW + xc] : make_uint2(0u,0u);
      sb[j] = vs4[j] ? hb[(size_t)yr*WW + xc] : make_uint2(0u,0u);
    }
    #pragma unroll
    for(int j=0; j<4; ++j){
      int y = y0 + g*4 + j;
      int ny = min(y+GR, HH-1) - max(y-GR, 0) + 1;
      float rc = 1.f/(float)(nx*ny);
      float mI=s0*rc, mP=s1*rc, mIp=s2*rc, mII=s3*rc;
      float va = (mIp - mI*mP) / (mII - mI*mI + 1e-3f);
      float vb = mP - va*mI;
      abb[(size_t)y*WW + xc] = pack_h2(va, vb);
      if(va4[j]){ float4 v = unpack_h4(ad[j]); s0+=v.x; s1+=v.y; s2+=v.z; s3+=v.w; }
      if(vs4[j]){ float4 v = unpack_h4(sb[j]); s0-=v.x; s1-=v.y; s2-=v.z; s3-=v.w; }
    }
  }
}

// ---------------- vertical sums of (a,b) + pyramid -> T -> final composite ----------------
__global__ void k_final(const u32* __restrict__ hab, const float2* __restrict__ P2,
                        const u16* __restrict__ imgh,
                        const float* __restrict__ A, float* __restrict__ out){
  int xc = blockIdx.x*256 + threadIdx.x;
  int n = blockIdx.z;
  int y0 = blockIdx.y*8;
  float A0=A[n*8+0], A1=A[n*8+1], A2=A[n*8+2];
  const u32* hb = hab + (size_t)n*HWSZ;
  const float2* pb = P2 + (size_t)n*64*WW + xc;
  int nx = min(xc+GR, WW-1) - max(xc-GR, 0) + 1;
  const u16* ib = imgh + (size_t)n*3*HWSZ;
  float* ob = out + (size_t)n*3*HWSZ;

  int lo = y0-GR; if(lo < 0) lo = 0;
  int hi = y0+GR; if(hi > HH-1) hi = HH-1;
  int g_lo = lo >> 3;
  int g_hi = ((hi+1) >> 3) - 1;
  float sa=0.f, sb=0.f;
  #pragma unroll 6
  for(int g=g_lo; g<=g_hi; ++g){
    float2 v = pb[(size_t)g*WW];
    sa+=v.x; sb+=v.y;
  }
  for(int y=(g_hi+1)*8; y<=hi; ++y){
    float2 v = unpack_h2(hb[(size_t)y*WW + xc]);
    sa+=v.x; sb+=v.y;
  }

  #pragma unroll
  for(int g=0; g<2; ++g){
    u32 ad[4], su[4];
    bool va4[4], vs4[4];
    #pragma unroll
    for(int j=0; j<4; ++j){
      int y = y0 + g*4 + j;
      int ya = y+GR+1, yr = y-GR;
      va4[j] = (ya < HH); vs4[j] = (yr >= 0);
      ad[j] = va4[j] ? hb[(size_t)ya*WW + xc] : 0u;
      su[j] = vs4[j] ? hb[(size_t)yr*WW + xc] : 0u;
    }
    #pragma unroll
    for(int j=0; j<4; ++j){
      int y = y0 + g*4 + j;
      int ny = min(y+GR, HH-1) - max(y-GR, 0) + 1;
      float rc = 1.f/(float)(nx*ny);
      size_t oy = (size_t)y*WW + xc;
      float i0 = h2f(ib[oy]), i1 = h2f(ib[oy+HWSZ]), i2 = h2f(ib[oy+2*HWSZ]);
      float g2 = (0.2989f*(2.f*i0-1.f) + 0.587f*(2.f*i1-1.f) + 0.114f*(2.f*i2-1.f) + 1.f)*0.5f;
      float T = (sa*g2 + sb)*rc;
      float rT = 1.0f / T;
      __builtin_nontemporal_store((i0-A0)*rT + A0, &ob[oy]);
      __builtin_nontemporal_store((i1-A1)*rT + A1, &ob[oy+HWSZ]);
      __builtin_nontemporal_store((i2-A2)*rT + A2, &ob[oy+2*HWSZ]);
      if(va4[j]){ float2 v = unpack_h2(ad[j]); sa+=v.x; sb+=v.y; }
      if(vs4[j]){ float2 v = unpack_h2(su[j]); sa-=v.x; sb-=v.y; }
    }
  }
}

extern "C" void kernel_launch(void* const* d_in, const int* in_sizes, int n_in,
                              void* d_out, int out_size, void* d_ws, size_t ws_size,
                              hipStream_t stream) {
  const float* x = (const float*)d_in[0];
  float* out = (float*)d_out;
  char* ws = (char*)d_ws;
  const size_t MB = 1u<<20;

  // region map (80.6 MiB + selection):
  u16*   imgh  = (u16*)(ws + 0);            // 24 MiB, live whole pass
  u16*   guidh = (u16*)(ws + 24*MB);        //  8 MiB, prep -> hbox4
  // region A (32 MiB):
  float* rowm  = (float*)(ws + 32*MB);      // 16 MiB, prep -> colmin_dark
  float* dark  = (float*)(ws + 48*MB);      // 16 MiB, colmin_dark -> sel4
  uint2* h4    = (uint2*)(ws + 32*MB);      // 32 MiB, hbox4 -> vbox   (over rowm+dark)
  u32*   hab   = (u32*)(ws + 32*MB);        // 16 MiB, hbox2 -> final  (over h4)
  // region B (16 MiB):
  u16*   rowm2 = (u16*)(ws + 64*MB);        //  8 MiB, rowmin2 -> hbox4 (live!)
  float4* P4   = (float4*)(ws + 72*MB);     //  8 MiB, hbox4 -> vbox
  float2* P2   = (float2*)(ws + 64*MB);     //  4 MiB, hbox2 -> final (over rowm2, dead after hbox4)
  // ab scratch lives in d_out (overwritten by k_final, which doesn't read it)
  u32*   ab    = (u32*)out;                 // 16 MiB
  // selection state (no aliasing: sel4 reads hist1 while writing ties)
  char* sm = ws + 80*MB;
  u32* hist1  = (u32*)sm;                             // 512 KiB
  u32* ties_i = (u32*)(sm + 512*1024);                // 768 KiB (16*12288*4)
  u32* ties_v = (u32*)(sm + 512*1024 + 768*1024);     // 768 KiB
  u32* st     = (u32*)(sm + 2048*1024);               // 1 KiB
  float* sums = (float*)(sm + 2048*1024 + 1024);
  float* Abuf = (float*)(sm + 2048*1024 + 1024 + 512);
  int zwords = (2048*1024 + 1024 + 512 + 512) / 4;    // zero hist1+ties+st+sums+Abuf

  // 1. prep: img16 + guid16 + row-min (f32, exact) + state zero
  k_prep<<<dim3(NIMG*HH), dim3(512), 0, stream>>>(x, imgh, guidh, rowm, (u32*)sm, zwords);
  // 2. col-min dark
  k_colmin_dark<<<dim3(HH, NIMG), dim3(128), 0, stream>>>(rowm, dark);
  // 3. atmospheric light: hist1, sel4(+csel1, bin-level ties), sel5(exact two-phase)
  k_hist1<<<dim3(NIMG, 8), dim3(1024), 0, stream>>>(dark, hist1);
  k_sel4<<<dim3(NIMG, 8), dim3(1024), 0, stream>>>(dark, x, hist1, st, sums, ties_i, ties_v);
  k_sel5<<<dim3(NIMG), dim3(1024), 0, stream>>>(x, st, sums, ties_i, ties_v, Abuf);
  // 4. transmission raw (row-min only; col-min fused into hbox4)
  k_rowmin2<<<dim3(NIMG*HH), dim3(512), 0, stream>>>(imgh, Abuf, rowm2);
  // 5. guided filter round 1 (colmin_pT fused into hbox4 prologue)
  k_hbox4<<<dim3(NIMG*64), dim3(512), 0, stream>>>(guidh, rowm2, h4, P4);
  k_vbox_ab<<<dim3(2, HH/8, NIMG), dim3(256), 0, stream>>>(h4, P4, ab);
  // 6. guided filter round 2 -> T -> final output
  k_hbox2<<<dim3(NIMG*64), dim3(512), 0, stream>>>(ab, hab, P2);
  k_final<<<dim3(2, HH/8, NIMG), dim3(256), 0, stream>>>(hab, P2, imgh, Abuf, out);
}

// Round 15
// 195.325 us; speedup vs baseline: 1.0942x; 1.0942x over previous
//
#include <hip/hip_runtime.h>
#include <hip/hip_fp16.h>

typedef unsigned int u32;
typedef unsigned short u16;

#define NIMG 16
#define HH 512
#define WW 512
#define HWSZ (HH*WW)
#define TOPN 2621u
#define TIE_CAP 12288
#define GR 40

// ---------- f16 packing helpers ----------
static __device__ inline u16 f2h(float v){ __half h=__float2half_rn(v); return *reinterpret_cast<u16*>(&h); }
static __device__ inline float h2f(u16 v){ __half h=*reinterpret_cast<__half*>(&v); return __half2float(h); }
static __device__ inline uint2 pack_h4(float4 S){
  __half2 lo = __floats2half2_rn(S.x, S.y);
  __half2 hi = __floats2half2_rn(S.z, S.w);
  uint2 r;
  r.x = *reinterpret_cast<unsigned int*>(&lo);
  r.y = *reinterpret_cast<unsigned int*>(&hi);
  return r;
}
static __device__ inline float4 unpack_h4(uint2 v){
  __half2 lo = *reinterpret_cast<__half2*>(&v.x);
  __half2 hi = *reinterpret_cast<__half2*>(&v.y);
  float2 A = __half22float2(lo), B = __half22float2(hi);
  return make_float4(A.x, A.y, B.x, B.y);
}
static __device__ inline u32 pack_h2(float a, float b){
  __half2 h = __floats2half2_rn(a, b);
  return *reinterpret_cast<unsigned int*>(&h);
}
static __device__ inline float2 unpack_h2(u32 v){
  __half2 h = *reinterpret_cast<__half2*>(&v);
  return __half22float2(h);
}

// ---------------- prep: x -> img16(3 planes), guid16, row-min f32 (dark path), zero state ----------------
__global__ void k_prep(const float* __restrict__ x, u16* __restrict__ imgh,
                       u16* __restrict__ guidh, float* __restrict__ rowm,
                       u32* __restrict__ state, int zwords){
  __shared__ float s[WW+14];
  int row = blockIdx.x; int n = row>>9; int y = row&511; int t = threadIdx.x;
  int zi = row*512 + t;
  if(zi < zwords) state[zi] = 0;
  const float* xb = x + (size_t)n*3*HWSZ + (size_t)y*WW + t;
  float x0=xb[0], x1=xb[HWSZ], x2=xb[2*HWSZ];
  float i0=(x0+1.f)*0.5f, i1=(x1+1.f)*0.5f, i2=(x2+1.f)*0.5f;
  size_t po = (size_t)n*3*HWSZ + (size_t)y*WW + t;
  imgh[po] = f2h(i0); imgh[po+HWSZ] = f2h(i1); imgh[po+2*HWSZ] = f2h(i2);
  float g = (0.2989f*x0 + 0.587f*x1 + 0.114f*x2 + 1.f)*0.5f;   // exact reference form
  size_t qo = (size_t)n*HWSZ + (size_t)y*WW + t;
  guidh[qo] = f2h(g);
  float m = fminf(i0, fminf(i1, i2));
  s[t+7] = m;
  if(t < 7) s[t] = 1.0f;
  if(t >= WW-7) s[t+14] = 1.0f;
  __syncthreads();
  float v = s[t];
  #pragma unroll
  for(int d=1; d<15; ++d) v = fminf(v, s[t+d]);
  rowm[qo] = v;
}

// ------- fused 15-tap col-min (dark, f32 exact) + hist1 (same granularity as old hist1) -------
// grid (8, NIMG), 1024 threads: thread = (col, sub); 32 output rows per thread.
__global__ void k_cmhist(const float* __restrict__ rowm, float* __restrict__ dark,
                         u32* __restrict__ hist1){
  __shared__ u32 h[8192];
  int yg = blockIdx.x, n = blockIdx.y, t = threadIdx.x;
  for(int i=t; i<8192; i+=1024) h[i] = 0;
  int col = t & 511, sub = t >> 9;
  int rs = yg*64 + sub*32;                 // output rows rs..rs+31
  const float* rb = rowm + (size_t)n*HWSZ + col;
  float val[46];
  #pragma unroll
  for(int r=0; r<46; ++r){
    int yy = rs - 7 + r;
    val[r] = (yy >= 0 && yy < HH) ? rb[(size_t)yy*WW] : 1.0f;
  }
  __syncthreads();                          // LDS hist zeroed
  float* db = dark + (size_t)n*HWSZ + col;
  #pragma unroll
  for(int k=0; k<32; ++k){
    float m = val[k];
    #pragma unroll
    for(int d=1; d<15; ++d) m = fminf(m, val[k+d]);
    db[(size_t)(rs+k)*WW] = m;
    u32 key = __float_as_uint(m);
    int b = (int)(key >> 10) - 0xFC000;
    b = max(0, min(8191, b));
    atomicAdd(&h[b], 1u);
  }
  __syncthreads();
  u32* gh = hist1 + n*8192;
  for(int i=t; i<8192; i+=1024) if(h[i]) atomicAdd(&gh[i], h[i]);
}

__device__ inline u32 block_scan_incl(u32 v, int t, u32* wsum){
  #pragma unroll
  for(int d=1; d<64; d<<=1){
    u32 u = __shfl_up(v, d);
    if((t & 63) >= d) v += u;
  }
  if((t & 63) == 63) wsum[t >> 6] = v;
  __syncthreads();
  u32 carry = 0;
  for(int w=0; w < (t >> 6); ++w) carry += wsum[w];
  return v + carry;
}

// ------- sel4 with csel1 prologue; sums over bins > bin_hi, ties = whole bin_hi bin -------
__global__ void k_sel4(const float* __restrict__ dark, const float* __restrict__ x,
                       const u32* __restrict__ hist1, u32* __restrict__ st,
                       float* __restrict__ sums, u32* __restrict__ ties_i,
                       u32* __restrict__ ties_v){
  __shared__ u32 wsum[16];
  __shared__ u32 bc[1];
  __shared__ float red[1024];
  int n = blockIdx.x, part = blockIdx.y, t = threadIdx.x;   // 1024 threads
  const u32* hh = hist1 + n*8192;
  u32 loc[8]; u32 ps = 0;
  #pragma unroll
  for(int k=0; k<8; ++k){
    loc[k] = hh[8191 - (t*8 + k)];
    ps += loc[k];
  }
  u32 incl = block_scan_incl(ps, t, wsum);
  u32 excl = incl - ps;
  if(excl < TOPN && incl >= TOPN){
    u32 cum = excl;
    #pragma unroll
    for(int k=0; k<8; ++k){
      if(cum + loc[k] >= TOPN){
        bc[0] = (u32)(8191 - (t*8+k));
        st[n*16+6] = TOPN - cum;      // k_need (racing identical writes: benign)
        break;
      }
      cum += loc[k];
    }
  }
  __syncthreads();
  int bin_hi = (int)bc[0];
  const u32* d = (const u32*)(dark + (size_t)n*HWSZ);
  const float* xb = x + (size_t)n*3*HWSZ;
  float a0=0.f, a1=0.f, a2=0.f;
  int per = HWSZ/8, i0 = part*per;
  for(int i=i0+t; i<i0+per; i+=1024){
    u32 key = d[i];
    int b = (int)(key >> 10) - 0xFC000;
    b = max(0, min(8191, b));
    if(b > bin_hi){
      a0 += xb[i]; a1 += xb[i+HWSZ]; a2 += xb[i+2*HWSZ];
    } else if(b == bin_hi){
      u32 pos = atomicAdd(&st[n*16+7], 1u);
      if(pos < TIE_CAP){ ties_i[n*TIE_CAP + pos] = (u32)i; ties_v[n*TIE_CAP + pos] = key; }
    }
  }
  red[t]=a0; __syncthreads();
  for(int s=512;s>0;s>>=1){ if(t<s) red[t]+=red[t+s]; __syncthreads(); }
  if(t==0) atomicAdd(&sums[n*8+0], red[0]);
  __syncthreads();
  red[t]=a1; __syncthreads();
  for(int s=512;s>0;s>>=1){ if(t<s) red[t]+=red[t+s]; __syncthreads(); }
  if(t==0) atomicAdd(&sums[n*8+1], red[0]);
  __syncthreads();
  red[t]=a2; __syncthreads();
  for(int s=512;s>0;s>>=1){ if(t<s) red[t]+=red[t+s]; __syncthreads(); }
  if(t==0) atomicAdd(&sums[n*8+2], red[0]);
}

// ---- sel5: exact top-k among bin ties: low-10-bit value search, then index cutoff ----
__global__ void k_sel5(const float* __restrict__ x, const u32* __restrict__ st,
                       const float* __restrict__ sums, const u32* __restrict__ ties_i,
                       const u32* __restrict__ ties_v, float* __restrict__ A){
  __shared__ u32 tl[TIE_CAP];
  __shared__ u16 kv[TIE_CAP];
  __shared__ u32 redu[1024];
  __shared__ float red[1024];
  __shared__ float fin[3];
  int n = blockIdx.x, t = threadIdx.x;   // 1024
  u32 k_need = st[n*16+6];
  u32 m = st[n*16+7]; if(m > TIE_CAP) m = TIE_CAP;
  const float* xb = x + (size_t)n*3*HWSZ;
  for(u32 e=t; e<m; e+=1024){
    tl[e] = ties_i[n*TIE_CAP + e];
    kv[e] = (u16)(ties_v[n*TIE_CAP + e] & 1023u);   // within one bin only low 10 bits differ
  }
  __syncthreads();
  // phase 1: vstar = k_need-th largest low-bits value, search [0,1023]
  u32 vlo = 0u, vhi = 1023u;
  while(vlo < vhi){
    u32 mid = (vlo + vhi + 1u) >> 1;
    u32 c = 0;
    for(u32 e=t; e<m; e+=1024) c += ((u32)kv[e] >= mid) ? 1u : 0u;
    redu[t] = c; __syncthreads();
    for(int s=512;s>0;s>>=1){ if(t<s) redu[t]+=redu[t+s]; __syncthreads(); }
    u32 total = redu[0]; __syncthreads();
    if(total >= k_need) vlo = mid; else vhi = mid - 1u;
  }
  u32 vstar = vlo;
  {
    u32 c = 0;
    for(u32 e=t; e<m; e+=1024) c += ((u32)kv[e] > vstar) ? 1u : 0u;
    redu[t] = c; __syncthreads();
    for(int s=512;s>0;s>>=1){ if(t<s) redu[t]+=redu[t+s]; __syncthreads(); }
  }
  u32 cnt_gt = redu[0]; __syncthreads();
  u32 k2 = k_need - cnt_gt;
  // phase 2: smallest C with count(kv==vstar && idx<C) >= k2
  u32 lo = 0, hi = HWSZ;
  while(lo < hi){
    u32 mid = (lo + hi) >> 1;
    u32 c = 0;
    for(u32 e=t; e<m; e+=1024) c += ((u32)kv[e] == vstar && tl[e] < mid) ? 1u : 0u;
    redu[t] = c; __syncthreads();
    for(int s=512;s>0;s>>=1){ if(t<s) redu[t]+=redu[t+s]; __syncthreads(); }
    u32 total = redu[0]; __syncthreads();
    if(total >= k2) hi = mid; else lo = mid + 1;
  }
  u32 C = lo;
  float a0=0.f, a1=0.f, a2=0.f;
  for(u32 e=t; e<m; e+=1024){
    u32 idx = tl[e];
    bool sel = ((u32)kv[e] > vstar) || ((u32)kv[e] == vstar && idx < C);
    if(sel){ a0 += xb[idx]; a1 += xb[idx+HWSZ]; a2 += xb[idx+2*HWSZ]; }
  }
  red[t]=a0; __syncthreads();
  for(int s=512;s>0;s>>=1){ if(t<s) red[t]+=red[t+s]; __syncthreads(); }
  if(t==0) fin[0]=red[0];
  __syncthreads();
  red[t]=a1; __syncthreads();
  for(int s=512;s>0;s>>=1){ if(t<s) red[t]+=red[t+s]; __syncthreads(); }
  if(t==0) fin[1]=red[0];
  __syncthreads();
  red[t]=a2; __syncthreads();
  for(int s=512;s>0;s>>=1){ if(t<s) red[t]+=red[t+s]; __syncthreads(); }
  if(t==0){
    fin[2]=red[0];
    for(int c=0;c<3;++c){
      float tot = sums[n*8+c] + fin[c];
      float Ac = (tot / 2621.0f + 1.0f) * 0.5f;
      A[n*8+c]   = Ac;
      A[n*8+4+c] = 1.0f / Ac;
    }
  }
}

// ---------------- rowmin of img/A (f16 img in, f16 out) ----------------
__global__ void k_rowmin2(const u16* __restrict__ imgh, const float* __restrict__ A,
                          u16* __restrict__ rowm2){
  __shared__ float s[WW+14];
  int row = blockIdx.x; int n = row>>9; int y = row&511; int t = threadIdx.x;
  float ia0=A[n*8+4], ia1=A[n*8+5], ia2=A[n*8+6];
  size_t po = (size_t)n*3*HWSZ + (size_t)y*WW + t;
  float i0=h2f(imgh[po]), i1=h2f(imgh[po+HWSZ]), i2=h2f(imgh[po+2*HWSZ]);
  float m = fminf(i0*ia0, fminf(i1*ia1, i2*ia2));
  s[t+7] = m;
  if(t < 7) s[t] = 1.0f;
  if(t >= WW-7) s[t+14] = 1.0f;
  __syncthreads();
  float v = s[t];
  #pragma unroll
  for(int d=1; d<15; ++d) v = fminf(v, s[t+d]);
  rowm2[(size_t)n*HWSZ + (size_t)y*WW + t] = f2h(v);
}

// -------- hbox4 with fused col-min prologue (reads rowm2) + horizontal box sums + P4 --------
__global__ void k_hbox4(const u16* __restrict__ guidh, const u16* __restrict__ rowm2,
                        uint2* __restrict__ h4, float4* __restrict__ P4){
  __shared__ float4 wsum[8];
  __shared__ float4 pref[WW];
  int b = blockIdx.x; int n = b >> 6; int g = b & 63; int t = threadIdx.x;
  int lane = t & 63, wv = t >> 6;
  const u16* rb = rowm2 + (size_t)n*HWSZ;
  float val[22];
  #pragma unroll
  for(int r=0; r<22; ++r){
    int yy = g*8 - 7 + r;
    val[r] = (yy >= 0 && yy < HH) ? h2f(rb[(size_t)yy*WW + t]) : 1.0f;
  }
  float Pv[8];
  #pragma unroll
  for(int j=0; j<8; ++j){
    float mn = val[j];
    #pragma unroll
    for(int d=1; d<15; ++d) mn = fminf(mn, val[j+d]);
    Pv[j] = h2f(f2h(1.0f - 0.95f*mn));   // replicate f16 round-trip exactly
  }
  float4 psum = {0.f,0.f,0.f,0.f};
  for(int j=0; j<8; ++j){
    int y = g*8 + j;
    size_t off = (size_t)n*HWSZ + (size_t)y*WW + t;
    float I = h2f(guidh[off]);
    float P = Pv[j];
    float4 s; s.x = I; s.y = P; s.z = I*P; s.w = I*I;
    #pragma unroll
    for(int d=1; d<64; d<<=1){
      float ux=__shfl_up(s.x,d), uy=__shfl_up(s.y,d), uz=__shfl_up(s.z,d), uw=__shfl_up(s.w,d);
      if(lane >= d){ s.x+=ux; s.y+=uy; s.z+=uz; s.w+=uw; }
    }
    if(lane == 63) wsum[wv] = s;
    __syncthreads();
    float4 c = {0.f,0.f,0.f,0.f};
    for(int w=0; w<wv; ++w){ float4 q=wsum[w]; c.x+=q.x; c.y+=q.y; c.z+=q.z; c.w+=q.w; }
    s.x+=c.x; s.y+=c.y; s.z+=c.z; s.w+=c.w;
    pref[t] = s;
    __syncthreads();
    int hi = min(t+GR, WW-1);
    float4 S = pref[hi];
    if(t >= GR+1){ float4 L = pref[t-GR-1]; S.x-=L.x; S.y-=L.y; S.z-=L.z; S.w-=L.w; }
    uint2 pk = pack_h4(S);
    h4[off] = pk;
    float4 r = unpack_h4(pk);     // accumulate ROUNDED values
    psum.x+=r.x; psum.y+=r.y; psum.z+=r.z; psum.w+=r.w;
    __syncthreads();
  }
  P4[((size_t)n*64 + g)*WW + t] = psum;
}

// -------- horizontal 81-tap box sums of (a,b); 8 rows/block; emits P2 partial --------
__global__ void k_hbox2(const u32* __restrict__ ab, u32* __restrict__ hab,
                        float2* __restrict__ P2){
  __shared__ float2 wsum[8];
  __shared__ float2 pref[WW];
  int b = blockIdx.x; int n = b >> 6; int g = b & 63; int t = threadIdx.x;
  int lane = t & 63, wv = t >> 6;
  float2 psum = {0.f,0.f};
  for(int j=0; j<8; ++j){
    int y = g*8 + j;
    size_t off = (size_t)n*HWSZ + (size_t)y*WW + t;
    float2 s = unpack_h2(ab[off]);
    #pragma unroll
    for(int d=1; d<64; d<<=1){
      float ux=__shfl_up(s.x,d), uy=__shfl_up(s.y,d);
      if(lane >= d){ s.x+=ux; s.y+=uy; }
    }
    if(lane == 63) wsum[wv] = s;
    __syncthreads();
    float2 c = {0.f,0.f};
    for(int w=0; w<wv; ++w){ float2 q=wsum[w]; c.x+=q.x; c.y+=q.y; }
    s.x+=c.x; s.y+=c.y;
    pref[t] = s;
    __syncthreads();
    int hi = min(t+GR, WW-1);
    float2 S = pref[hi];
    if(t >= GR+1){ float2 L = pref[t-GR-1]; S.x-=L.x; S.y-=L.y; }
    u32 pk = pack_h2(S.x, S.y);
    hab[off] = pk;
    float2 r = unpack_h2(pk);
    psum.x+=r.x; psum.y+=r.y;
    __syncthreads();
  }
  P2[((size_t)n*64 + g)*WW + t] = psum;
}

// ---------------- vertical 81-tap running sums (pyramid init, y-chunk 8) -> a,b ----------------
__global__ void k_vbox_ab(const uint2* __restrict__ h4, const float4* __restrict__ P4,
                          u32* __restrict__ ab){
  int xc = blockIdx.x*256 + threadIdx.x;
  int n = blockIdx.z;
  int y0 = blockIdx.y*8;
  const uint2* hb = h4 + (size_t)n*HWSZ;
  const float4* pb = P4 + (size_t)n*64*WW + xc;
  u32* abb = ab + (size_t)n*HWSZ;
  int nx = min(xc+GR, WW-1) - max(xc-GR, 0) + 1;

  int lo = y0-GR; if(lo < 0) lo = 0;
  int hi = y0+GR; if(hi > HH-1) hi = HH-1;
  int g_lo = lo >> 3;
  int g_hi = ((hi+1) >> 3) - 1;
  float s0=0.f, s1=0.f, s2=0.f, s3=0.f;
  #pragma unroll 6
  for(int g=g_lo; g<=g_hi; ++g){
    float4 v = pb[(size_t)g*WW];
    s0+=v.x; s1+=v.y; s2+=v.z; s3+=v.w;
  }
  for(int y=(g_hi+1)*8; y<=hi; ++y){
    float4 v = unpack_h4(hb[(size_t)y*WW + xc]);
    s0+=v.x; s1+=v.y; s2+=v.z; s3+=v.w;
  }

  #pragma unroll
  for(int g=0; g<2; ++g){
    uint2 ad[4], sb[4];
    bool va4[4], vs4[4];
    #pragma unroll
    for(int j=0; j<4; ++j){
      int y = y0 + g*4 + j;
      int ya = y+GR+1, yr = y-GR;
      va4[j] = (ya < HH); vs4[j] = (yr >= 0);
      ad[j] = va4[j] ? hb[(size_t)ya*WW + xc] : make_uint2(0u,0u);
      sb[j] = vs4[j] ? hb[(size_t)yr*WW + xc] : make_uint2(0u,0u);
    }
    #pragma unroll
    for(int j=0; j<4; ++j){
      int y = y0 + g*4 + j;
      int ny = min(y+GR, HH-1) - max(y-GR, 0) + 1;
      float rc = 1.f/(float)(nx*ny);
      float mI=s0*rc, mP=s1*rc, mIp=s2*rc, mII=s3*rc;
      float va = (mIp - mI*mP) / (mII - mI*mI + 1e-3f);
      float vb = mP - va*mI;
      abb[(size_t)y*WW + xc] = pack_h2(va, vb);
      if(va4[j]){ float4 v = unpack_h4(ad[j]); s0+=v.x; s1+=v.y; s2+=v.z; s3+=v.w; }
      if(vs4[j]){ float4 v = unpack_h4(sb[j]); s0-=v.x; s1-=v.y; s2-=v.z; s3-=v.w; }
    }
  }
}

// ---------------- vertical sums of (a,b) + pyramid -> T -> final composite ----------------
__global__ void k_final(const u32* __restrict__ hab, const float2* __restrict__ P2,
                        const u16* __restrict__ imgh,
                        const float* __restrict__ A, float* __restrict__ out){
  int xc = blockIdx.x*256 + threadIdx.x;
  int n = blockIdx.z;
  int y0 = blockIdx.y*8;
  float A0=A[n*8+0], A1=A[n*8+1], A2=A[n*8+2];
  const u32* hb = hab + (size_t)n*HWSZ;
  const float2* pb = P2 + (size_t)n*64*WW + xc;
  int nx = min(xc+GR, WW-1) - max(xc-GR, 0) + 1;
  const u16* ib = imgh + (size_t)n*3*HWSZ;
  float* ob = out + (size_t)n*3*HWSZ;

  int lo = y0-GR; if(lo < 0) lo = 0;
  int hi = y0+GR; if(hi > HH-1) hi = HH-1;
  int g_lo = lo >> 3;
  int g_hi = ((hi+1) >> 3) - 1;
  float sa=0.f, sb=0.f;
  #pragma unroll 6
  for(int g=g_lo; g<=g_hi; ++g){
    float2 v = pb[(size_t)g*WW];
    sa+=v.x; sb+=v.y;
  }
  for(int y=(g_hi+1)*8; y<=hi; ++y){
    float2 v = unpack_h2(hb[(size_t)y*WW + xc]);
    sa+=v.x; sb+=v.y;
  }

  #pragma unroll
  for(int g=0; g<2; ++g){
    u32 ad[4], su[4];
    bool va4[4], vs4[4];
    #pragma unroll
    for(int j=0; j<4; ++j){
      int y = y0 + g*4 + j;
      int ya = y+GR+1, yr = y-GR;
      va4[j] = (ya < HH); vs4[j] = (yr >= 0);
      ad[j] = va4[j] ? hb[(size_t)ya*WW + xc] : 0u;
      su[j] = vs4[j] ? hb[(size_t)yr*WW + xc] : 0u;
    }
    #pragma unroll
    for(int j=0; j<4; ++j){
      int y = y0 + g*4 + j;
      int ny = min(y+GR, HH-1) - max(y-GR, 0) + 1;
      float rc = 1.f/(float)(nx*ny);
      size_t oy = (size_t)y*WW + xc;
      float i0 = h2f(ib[oy]), i1 = h2f(ib[oy+HWSZ]), i2 = h2f(ib[oy+2*HWSZ]);
      float g2 = (0.2989f*(2.f*i0-1.f) + 0.587f*(2.f*i1-1.f) + 0.114f*(2.f*i2-1.f) + 1.f)*0.5f;
      float T = (sa*g2 + sb)*rc;
      float rT = 1.0f / T;
      __builtin_nontemporal_store((i0-A0)*rT + A0, &ob[oy]);
      __builtin_nontemporal_store((i1-A1)*rT + A1, &ob[oy+HWSZ]);
      __builtin_nontemporal_store((i2-A2)*rT + A2, &ob[oy+2*HWSZ]);
      if(va4[j]){ float2 v = unpack_h2(ad[j]); sa+=v.x; sb+=v.y; }
      if(vs4[j]){ float2 v = unpack_h2(su[j]); sa-=v.x; sb-=v.y; }
    }
  }
}

extern "C" void kernel_launch(void* const* d_in, const int* in_sizes, int n_in,
                              void* d_out, int out_size, void* d_ws, size_t ws_size,
                              hipStream_t stream) {
  const float* x = (const float*)d_in[0];
  float* out = (float*)d_out;
  char* ws = (char*)d_ws;
  const size_t MB = 1u<<20;

  // region map (80.6 MiB + selection):
  u16*   imgh  = (u16*)(ws + 0);            // 24 MiB, live whole pass
  u16*   guidh = (u16*)(ws + 24*MB);        //  8 MiB, prep -> hbox4
  // region A (32 MiB):
  float* rowm  = (float*)(ws + 32*MB);      // 16 MiB, prep -> cmhist
  float* dark  = (float*)(ws + 48*MB);      // 16 MiB, cmhist -> sel4
  uint2* h4    = (uint2*)(ws + 32*MB);      // 32 MiB, hbox4 -> vbox   (over rowm+dark)
  u32*   hab   = (u32*)(ws + 32*MB);        // 16 MiB, hbox2 -> final  (over h4)
  // region B (16 MiB):
  u16*   rowm2 = (u16*)(ws + 64*MB);        //  8 MiB, rowmin2 -> hbox4 (live!)
  float4* P4   = (float4*)(ws + 72*MB);     //  8 MiB, hbox4 -> vbox
  float2* P2   = (float2*)(ws + 64*MB);     //  4 MiB, hbox2 -> final (over rowm2, dead after hbox4)
  // ab scratch lives in d_out (overwritten by k_final, which doesn't read it)
  u32*   ab    = (u32*)out;                 // 16 MiB
  // selection state (no aliasing: sel4 reads hist1 while writing ties)
  char* sm = ws + 80*MB;
  u32* hist1  = (u32*)sm;                             // 512 KiB
  u32* ties_i = (u32*)(sm + 512*1024);                // 768 KiB (16*12288*4)
  u32* ties_v = (u32*)(sm + 512*1024 + 768*1024);     // 768 KiB
  u32* st     = (u32*)(sm + 2048*1024);               // 1 KiB
  float* sums = (float*)(sm + 2048*1024 + 1024);
  float* Abuf = (float*)(sm + 2048*1024 + 1024 + 512);
  int zwords = (2048*1024 + 1024 + 512 + 512) / 4;    // zero hist1+ties+st+sums+Abuf

  // 1. prep: img16 + guid16 + row-min (f32, exact) + state zero
  k_prep<<<dim3(NIMG*HH), dim3(512), 0, stream>>>(x, imgh, guidh, rowm, (u32*)sm, zwords);
  // 2. fused col-min dark + hist1 (same LDS-hist granularity as old standalone hist1)
  k_cmhist<<<dim3(8, NIMG), dim3(1024), 0, stream>>>(rowm, dark, hist1);
  // 3. atmospheric light: sel4(+csel1, bin-level ties), sel5(exact two-phase)
  k_sel4<<<dim3(NIMG, 8), dim3(1024), 0, stream>>>(dark, x, hist1, st, sums, ties_i, ties_v);
  k_sel5<<<dim3(NIMG), dim3(1024), 0, stream>>>(x, st, sums, ties_i, ties_v, Abuf);
  // 4. transmission raw (row-min only; col-min fused into hbox4)
  k_rowmin2<<<dim3(NIMG*HH), dim3(512), 0, stream>>>(imgh, Abuf, rowm2);
  // 5. guided filter round 1 (colmin_pT fused into hbox4 prologue)
  k_hbox4<<<dim3(NIMG*64), dim3(512), 0, stream>>>(guidh, rowm2, h4, P4);
  k_vbox_ab<<<dim3(2, HH/8, NIMG), dim3(256), 0, stream>>>(h4, P4, ab);
  // 6. guided filter round 2 -> T -> final output
  k_hbox2<<<dim3(NIMG*64), dim3(512), 0, stream>>>(ab, hab, P2);
  k_final<<<dim3(2, HH/8, NIMG), dim3(256), 0, stream>>>(hab, P2, imgh, Abuf, out);
}

// Round 17
// 193.610 us; speedup vs baseline: 1.1039x; 1.0089x over previous
//
#include <hip/hip_runtime.h>
#include <hip/hip_fp16.h>

typedef unsigned int u32;
typedef unsigned short u16;
typedef unsigned long long u64;

#define NIMG 16
#define HH 512
#define WW 512
#define HWSZ (HH*WW)
#define TOPN 2621u
#define TIE_CAP 12288
#define GR 40

// ---------- f16 packing helpers ----------
static __device__ inline u16 f2h(float v){ __half h=__float2half_rn(v); return *reinterpret_cast<u16*>(&h); }
static __device__ inline float h2f(u16 v){ __half h=*reinterpret_cast<__half*>(&v); return __half2float(h); }
static __device__ inline uint2 pack_h4(float4 S){
  __half2 lo = __floats2half2_rn(S.x, S.y);
  __half2 hi = __floats2half2_rn(S.z, S.w);
  uint2 r;
  r.x = *reinterpret_cast<unsigned int*>(&lo);
  r.y = *reinterpret_cast<unsigned int*>(&hi);
  return r;
}
static __device__ inline float4 unpack_h4(uint2 v){
  __half2 lo = *reinterpret_cast<__half2*>(&v.x);
  __half2 hi = *reinterpret_cast<__half2*>(&v.y);
  float2 A = __half22float2(lo), B = __half22float2(hi);
  return make_float4(A.x, A.y, B.x, B.y);
}
static __device__ inline u32 pack_h2(float a, float b){
  __half2 h = __floats2half2_rn(a, b);
  return *reinterpret_cast<unsigned int*>(&h);
}
static __device__ inline float2 unpack_h2(u32 v){
  __half2 h = *reinterpret_cast<__half2*>(&v);
  return __half22float2(h);
}
static __device__ inline void nt_store_f2(float a, float b, float* p){
  float2 v = make_float2(a, b);
  __builtin_nontemporal_store(*reinterpret_cast<u64*>(&v), reinterpret_cast<u64*>(p));
}

// ------- prep (2 px/thread): x -> img16, guid16, row-min f32, zero state -------
__global__ void k_prep(const float* __restrict__ x, u32* __restrict__ imgh2,
                       u32* __restrict__ guidh2, float2* __restrict__ rowmo,
                       u32* __restrict__ state, int zwords){
  __shared__ float s[WW+14];
  int row = blockIdx.x; int n = row>>9; int y = row&511; int t = threadIdx.x;  // 256
  int zi = row*256 + t;
  if(zi < zwords) state[zi] = 0;
  const float2* xb = (const float2*)(x + (size_t)n*3*HWSZ + (size_t)y*WW);
  float2 x0 = xb[t], x1 = xb[t + HWSZ/2], x2 = xb[t + HWSZ];
  float i0a=(x0.x+1.f)*0.5f, i0b=(x0.y+1.f)*0.5f;
  float i1a=(x1.x+1.f)*0.5f, i1b=(x1.y+1.f)*0.5f;
  float i2a=(x2.x+1.f)*0.5f, i2b=(x2.y+1.f)*0.5f;
  size_t pb = ((size_t)n*3*HWSZ + (size_t)y*WW)/2 + t;
  imgh2[pb]          = pack_h2(i0a, i0b);
  imgh2[pb+HWSZ/2]   = pack_h2(i1a, i1b);
  imgh2[pb+HWSZ]     = pack_h2(i2a, i2b);
  float ga = (0.2989f*x0.x + 0.587f*x1.x + 0.114f*x2.x + 1.f)*0.5f;
  float gb = (0.2989f*x0.y + 0.587f*x1.y + 0.114f*x2.y + 1.f)*0.5f;
  size_t qb = ((size_t)n*HWSZ + (size_t)y*WW)/2 + t;
  guidh2[qb] = pack_h2(ga, gb);
  s[2*t+7] = fminf(i0a, fminf(i1a, i2a));
  s[2*t+8] = fminf(i0b, fminf(i1b, i2b));
  if(t < 7){ s[t] = 1.0f; s[WW+7+t] = 1.0f; }
  __syncthreads();
  float mm = s[2*t+1];
  #pragma unroll
  for(int d=2; d<15; ++d) mm = fminf(mm, s[2*t+d]);
  float v0 = fminf(s[2*t], mm);
  float v1 = fminf(mm, s[2*t+15]);
  rowmo[qb] = make_float2(v0, v1);
}

// ------- fused 15-tap col-min (dark, f32 exact) + hist1 -------
__global__ void k_cmhist(const float* __restrict__ rowm, float* __restrict__ dark,
                         u32* __restrict__ hist1){
  __shared__ u32 h[8192];
  int yg = blockIdx.x, n = blockIdx.y, t = threadIdx.x;
  for(int i=t; i<8192; i+=1024) h[i] = 0;
  int col = t & 511, sub = t >> 9;
  int rs = yg*64 + sub*32;                 // output rows rs..rs+31
  const float* rb = rowm + (size_t)n*HWSZ + col;
  float val[46];
  #pragma unroll
  for(int r=0; r<46; ++r){
    int yy = rs - 7 + r;
    val[r] = (yy >= 0 && yy < HH) ? rb[(size_t)yy*WW] : 1.0f;
  }
  __syncthreads();                          // LDS hist zeroed
  float* db = dark + (size_t)n*HWSZ + col;
  #pragma unroll
  for(int k=0; k<32; ++k){
    float m = val[k];
    #pragma unroll
    for(int d=1; d<15; ++d) m = fminf(m, val[k+d]);
    db[(size_t)(rs+k)*WW] = m;
    u32 key = __float_as_uint(m);
    int b = (int)(key >> 10) - 0xFC000;
    b = max(0, min(8191, b));
    atomicAdd(&h[b], 1u);
  }
  __syncthreads();
  u32* gh = hist1 + n*8192;
  for(int i=t; i<8192; i+=1024) if(h[i]) atomicAdd(&gh[i], h[i]);
}

__device__ inline u32 block_scan_incl(u32 v, int t, u32* wsum){
  #pragma unroll
  for(int d=1; d<64; d<<=1){
    u32 u = __shfl_up(v, d);
    if((t & 63) >= d) v += u;
  }
  if((t & 63) == 63) wsum[t >> 6] = v;
  __syncthreads();
  u32 carry = 0;
  for(int w=0; w < (t >> 6); ++w) carry += wsum[w];
  return v + carry;
}

// ------- sel4 with csel1 prologue; sums over bins > bin_hi, ties = whole bin_hi bin -------
__global__ void k_sel4(const float* __restrict__ dark, const float* __restrict__ x,
                       const u32* __restrict__ hist1, u32* __restrict__ st,
                       float* __restrict__ sums, u32* __restrict__ ties_i,
                       u32* __restrict__ ties_v){
  __shared__ u32 wsum[16];
  __shared__ u32 bc[1];
  __shared__ float red[1024];
  int n = blockIdx.x, part = blockIdx.y, t = threadIdx.x;   // 1024 threads
  const u32* hh = hist1 + n*8192;
  u32 loc[8]; u32 ps = 0;
  #pragma unroll
  for(int k=0; k<8; ++k){
    loc[k] = hh[8191 - (t*8 + k)];
    ps += loc[k];
  }
  u32 incl = block_scan_incl(ps, t, wsum);
  u32 excl = incl - ps;
  if(excl < TOPN && incl >= TOPN){
    u32 cum = excl;
    #pragma unroll
    for(int k=0; k<8; ++k){
      if(cum + loc[k] >= TOPN){
        bc[0] = (u32)(8191 - (t*8+k));
        st[n*16+6] = TOPN - cum;      // k_need (racing identical writes: benign)
        break;
      }
      cum += loc[k];
    }
  }
  __syncthreads();
  int bin_hi = (int)bc[0];
  const u32* d = (const u32*)(dark + (size_t)n*HWSZ);
  const float* xb = x + (size_t)n*3*HWSZ;
  float a0=0.f, a1=0.f, a2=0.f;
  int per = HWSZ/8, i0 = part*per;
  for(int i=i0+t; i<i0+per; i+=1024){
    u32 key = d[i];
    int b = (int)(key >> 10) - 0xFC000;
    b = max(0, min(8191, b));
    if(b > bin_hi){
      a0 += xb[i]; a1 += xb[i+HWSZ]; a2 += xb[i+2*HWSZ];
    } else if(b == bin_hi){
      u32 pos = atomicAdd(&st[n*16+7], 1u);
      if(pos < TIE_CAP){ ties_i[n*TIE_CAP + pos] = (u32)i; ties_v[n*TIE_CAP + pos] = key; }
    }
  }
  red[t]=a0; __syncthreads();
  for(int s=512;s>0;s>>=1){ if(t<s) red[t]+=red[t+s]; __syncthreads(); }
  if(t==0) atomicAdd(&sums[n*8+0], red[0]);
  __syncthreads();
  red[t]=a1; __syncthreads();
  for(int s=512;s>0;s>>=1){ if(t<s) red[t]+=red[t+s]; __syncthreads(); }
  if(t==0) atomicAdd(&sums[n*8+1], red[0]);
  __syncthreads();
  red[t]=a2; __syncthreads();
  for(int s=512;s>0;s>>=1){ if(t<s) red[t]+=red[t+s]; __syncthreads(); }
  if(t==0) atomicAdd(&sums[n*8+2], red[0]);
}

// ---- sel5: exact top-k among bin ties: low-10-bit value search, then index cutoff ----
__global__ void k_sel5(const float* __restrict__ x, const u32* __restrict__ st,
                       const float* __restrict__ sums, const u32* __restrict__ ties_i,
                       const u32* __restrict__ ties_v, float* __restrict__ A){
  __shared__ u32 tl[TIE_CAP];
  __shared__ u16 kv[TIE_CAP];
  __shared__ u32 redu[1024];
  __shared__ float red[1024];
  __shared__ float fin[3];
  int n = blockIdx.x, t = threadIdx.x;   // 1024
  u32 k_need = st[n*16+6];
  u32 m = st[n*16+7]; if(m > TIE_CAP) m = TIE_CAP;
  const float* xb = x + (size_t)n*3*HWSZ;
  for(u32 e=t; e<m; e+=1024){
    tl[e] = ties_i[n*TIE_CAP + e];
    kv[e] = (u16)(ties_v[n*TIE_CAP + e] & 1023u);
  }
  __syncthreads();
  u32 vlo = 0u, vhi = 1023u;
  while(vlo < vhi){
    u32 mid = (vlo + vhi + 1u) >> 1;
    u32 c = 0;
    for(u32 e=t; e<m; e+=1024) c += ((u32)kv[e] >= mid) ? 1u : 0u;
    redu[t] = c; __syncthreads();
    for(int s=512;s>0;s>>=1){ if(t<s) redu[t]+=redu[t+s]; __syncthreads(); }
    u32 total = redu[0]; __syncthreads();
    if(total >= k_need) vlo = mid; else vhi = mid - 1u;
  }
  u32 vstar = vlo;
  {
    u32 c = 0;
    for(u32 e=t; e<m; e+=1024) c += ((u32)kv[e] > vstar) ? 1u : 0u;
    redu[t] = c; __syncthreads();
    for(int s=512;s>0;s>>=1){ if(t<s) redu[t]+=redu[t+s]; __syncthreads(); }
  }
  u32 cnt_gt = redu[0]; __syncthreads();
  u32 k2 = k_need - cnt_gt;
  u32 lo = 0, hi = HWSZ;
  while(lo < hi){
    u32 mid = (lo + hi) >> 1;
    u32 c = 0;
    for(u32 e=t; e<m; e+=1024) c += ((u32)kv[e] == vstar && tl[e] < mid) ? 1u : 0u;
    redu[t] = c; __syncthreads();
    for(int s=512;s>0;s>>=1){ if(t<s) redu[t]+=redu[t+s]; __syncthreads(); }
    u32 total = redu[0]; __syncthreads();
    if(total >= k2) hi = mid; else lo = mid + 1;
  }
  u32 C = lo;
  float a0=0.f, a1=0.f, a2=0.f;
  for(u32 e=t; e<m; e+=1024){
    u32 idx = tl[e];
    bool sel = ((u32)kv[e] > vstar) || ((u32)kv[e] == vstar && idx < C);
    if(sel){ a0 += xb[idx]; a1 += xb[idx+HWSZ]; a2 += xb[idx+2*HWSZ]; }
  }
  red[t]=a0; __syncthreads();
  for(int s=512;s>0;s>>=1){ if(t<s) red[t]+=red[t+s]; __syncthreads(); }
  if(t==0) fin[0]=red[0];
  __syncthreads();
  red[t]=a1; __syncthreads();
  for(int s=512;s>0;s>>=1){ if(t<s) red[t]+=red[t+s]; __syncthreads(); }
  if(t==0) fin[1]=red[0];
  __syncthreads();
  red[t]=a2; __syncthreads();
  for(int s=512;s>0;s>>=1){ if(t<s) red[t]+=red[t+s]; __syncthreads(); }
  if(t==0){
    fin[2]=red[0];
    for(int c=0;c<3;++c){
      float tot = sums[n*8+c] + fin[c];
      float Ac = (tot / 2621.0f + 1.0f) * 0.5f;
      A[n*8+c]   = Ac;
      A[n*8+4+c] = 1.0f / Ac;
    }
  }
}

// ---------------- rowmin of img/A, 2 px/thread (packed u32 in/out) ----------------
__global__ void k_rowmin2(const u32* __restrict__ imgh2, const float* __restrict__ A,
                          u32* __restrict__ rowm2){
  __shared__ float s[WW+14];
  int row = blockIdx.x; int n = row>>9; int y = row&511; int t = threadIdx.x;  // 256
  float ia0=A[n*8+4], ia1=A[n*8+5], ia2=A[n*8+6];
  size_t pb = ((size_t)n*3*HWSZ + (size_t)y*WW)/2 + t;
  float2 i0 = unpack_h2(imgh2[pb]);
  float2 i1 = unpack_h2(imgh2[pb+HWSZ/2]);
  float2 i2 = unpack_h2(imgh2[pb+HWSZ]);
  s[2*t+7] = fminf(i0.x*ia0, fminf(i1.x*ia1, i2.x*ia2));
  s[2*t+8] = fminf(i0.y*ia0, fminf(i1.y*ia1, i2.y*ia2));
  if(t < 7){ s[t] = 1.0f; s[WW+7+t] = 1.0f; }
  __syncthreads();
  float mm = s[2*t+1];
  #pragma unroll
  for(int d=2; d<15; ++d) mm = fminf(mm, s[2*t+d]);
  float v0 = fminf(s[2*t], mm);
  float v1 = fminf(mm, s[2*t+15]);
  rowm2[((size_t)n*HWSZ + (size_t)y*WW)/2 + t] = pack_h2(v0, v1);
}

// -------- hbox4 with fused col-min prologue (reads rowm2) + horizontal box sums + P4 --------
__global__ void k_hbox4(const u16* __restrict__ guidh, const u16* __restrict__ rowm2,
                        uint2* __restrict__ h4, float4* __restrict__ P4){
  __shared__ float4 wsum[8];
  __shared__ float4 pref[WW];
  int b = blockIdx.x; int n = b >> 6; int g = b & 63; int t = threadIdx.x;
  int lane = t & 63, wv = t >> 6;
  const u16* rb = rowm2 + (size_t)n*HWSZ;
  float val[22];
  #pragma unroll
  for(int r=0; r<22; ++r){
    int yy = g*8 - 7 + r;
    val[r] = (yy >= 0 && yy < HH) ? h2f(rb[(size_t)yy*WW + t]) : 1.0f;
  }
  float Pv[8];
  #pragma unroll
  for(int j=0; j<8; ++j){
    float mn = val[j];
    #pragma unroll
    for(int d=1; d<15; ++d) mn = fminf(mn, val[j+d]);
    Pv[j] = h2f(f2h(1.0f - 0.95f*mn));   // replicate f16 round-trip exactly
  }
  float4 psum = {0.f,0.f,0.f,0.f};
  for(int j=0; j<8; ++j){
    int y = g*8 + j;
    size_t off = (size_t)n*HWSZ + (size_t)y*WW + t;
    float I = h2f(guidh[off]);
    float P = Pv[j];
    float4 s; s.x = I; s.y = P; s.z = I*P; s.w = I*I;
    #pragma unroll
    for(int d=1; d<64; d<<=1){
      float ux=__shfl_up(s.x,d), uy=__shfl_up(s.y,d), uz=__shfl_up(s.z,d), uw=__shfl_up(s.w,d);
      if(lane >= d){ s.x+=ux; s.y+=uy; s.z+=uz; s.w+=uw; }
    }
    if(lane == 63) wsum[wv] = s;
    __syncthreads();
    float4 c = {0.f,0.f,0.f,0.f};
    for(int w=0; w<wv; ++w){ float4 q=wsum[w]; c.x+=q.x; c.y+=q.y; c.z+=q.z; c.w+=q.w; }
    s.x+=c.x; s.y+=c.y; s.z+=c.z; s.w+=c.w;
    pref[t] = s;
    __syncthreads();
    int hi = min(t+GR, WW-1);
    float4 S = pref[hi];
    if(t >= GR+1){ float4 L = pref[t-GR-1]; S.x-=L.x; S.y-=L.y; S.z-=L.z; S.w-=L.w; }
    uint2 pk = pack_h4(S);
    h4[off] = pk;
    float4 r = unpack_h4(pk);     // accumulate ROUNDED values
    psum.x+=r.x; psum.y+=r.y; psum.z+=r.z; psum.w+=r.w;
    __syncthreads();
  }
  P4[((size_t)n*64 + g)*WW + t] = psum;
}

// -------- horizontal 81-tap box sums of (a,b); 8 rows/block; emits P2 partial --------
__global__ void k_hbox2(const u32* __restrict__ ab, u32* __restrict__ hab,
                        float2* __restrict__ P2){
  __shared__ float2 wsum[8];
  __shared__ float2 pref[WW];
  int b = blockIdx.x; int n = b >> 6; int g = b & 63; int t = threadIdx.x;
  int lane = t & 63, wv = t >> 6;
  float2 psum = {0.f,0.f};
  for(int j=0; j<8; ++j){
    int y = g*8 + j;
    size_t off = (size_t)n*HWSZ + (size_t)y*WW + t;
    float2 s = unpack_h2(ab[off]);
    #pragma unroll
    for(int d=1; d<64; d<<=1){
      float ux=__shfl_up(s.x,d), uy=__shfl_up(s.y,d);
      if(lane >= d){ s.x+=ux; s.y+=uy; }
    }
    if(lane == 63) wsum[wv] = s;
    __syncthreads();
    float2 c = {0.f,0.f};
    for(int w=0; w<wv; ++w){ float2 q=wsum[w]; c.x+=q.x; c.y+=q.y; }
    s.x+=c.x; s.y+=c.y;
    pref[t] = s;
    __syncthreads();
    int hi = min(t+GR, WW-1);
    float2 S = pref[hi];
    if(t >= GR+1){ float2 L = pref[t-GR-1]; S.x-=L.x; S.y-=L.y; }
    u32 pk = pack_h2(S.x, S.y);
    hab[off] = pk;
    float2 r = unpack_h2(pk);
    psum.x+=r.x; psum.y+=r.y;
    __syncthreads();
  }
  P2[((size_t)n*64 + g)*WW + t] = psum;
}

// ---------------- vertical 81-tap running sums (pyramid init, y-chunk 8) -> a,b ----------------
__global__ void k_vbox_ab(const uint2* __restrict__ h4, const float4* __restrict__ P4,
                          u32* __restrict__ ab){
  int xc = blockIdx.x*256 + threadIdx.x;
  int n = blockIdx.z;
  int y0 = blockIdx.y*8;
  const uint2* hb = h4 + (size_t)n*HWSZ;
  const float4* pb = P4 + (size_t)n*64*WW + xc;
  u32* abb = ab + (size_t)n*HWSZ;
  int nx = min(xc+GR, WW-1) - max(xc-GR, 0) + 1;

  int lo = y0-GR; if(lo < 0) lo = 0;
  int hi = y0+GR; if(hi > HH-1) hi = HH-1;
  int g_lo = lo >> 3;
  int g_hi = ((hi+1) >> 3) - 1;
  float s0=0.f, s1=0.f, s2=0.f, s3=0.f;
  #pragma unroll 6
  for(int g=g_lo; g<=g_hi; ++g){
    float4 v = pb[(size_t)g*WW];
    s0+=v.x; s1+=v.y; s2+=v.z; s3+=v.w;
  }
  for(int y=(g_hi+1)*8; y<=hi; ++y){
    float4 v = unpack_h4(hb[(size_t)y*WW + xc]);
    s0+=v.x; s1+=v.y; s2+=v.z; s3+=v.w;
  }

  #pragma unroll
  for(int g=0; g<2; ++g){
    uint2 ad[4], sb[4];
    bool va4[4], vs4[4];
    #pragma unroll
    for(int j=0; j<4; ++j){
      int y = y0 + g*4 + j;
      int ya = y+GR+1, yr = y-GR;
      va4[j] = (ya < HH); vs4[j] = (yr >= 0);
      ad[j] = va4[j] ? hb[(size_t)ya*WW + xc] : make_uint2(0u,0u);
      sb[j] = vs4[j] ? hb[(size_t)yr*WW + xc] : make_uint2(0u,0u);
    }
    #pragma unroll
    for(int j=0; j<4; ++j){
      int y = y0 + g*4 + j;
      int ny = min(y+GR, HH-1) - max(y-GR, 0) + 1;
      float rc = 1.f/(float)(nx*ny);
      float mI=s0*rc, mP=s1*rc, mIp=s2*rc, mII=s3*rc;
      float va = (mIp - mI*mP) / (mII - mI*mI + 1e-3f);
      float vb = mP - va*mI;
      abb[(size_t)y*WW + xc] = pack_h2(va, vb);
      if(va4[j]){ float4 v = unpack_h4(ad[j]); s0+=v.x; s1+=v.y; s2+=v.z; s3+=v.w; }
      if(vs4[j]){ float4 v = unpack_h4(sb[j]); s0-=v.x; s1-=v.y; s2-=v.z; s3-=v.w; }
    }
  }
}

// ------- final, 2 px/thread: vertical sums of (a,b) + pyramid -> T -> composite -------
__global__ void k_final(const u32* __restrict__ hab, const float2* __restrict__ P2,
                        const u32* __restrict__ imgh2,
                        const float* __restrict__ A, float* __restrict__ out){
  int t = threadIdx.x;            // 256: column pair (2t, 2t+1)
  int y0 = blockIdx.x*8;
  int n = blockIdx.y;
  int c0 = 2*t, c1 = 2*t+1;
  float A0=A[n*8+0], A1=A[n*8+1], A2=A[n*8+2];
  const uint2* hb2 = (const uint2*)(hab + (size_t)n*HWSZ);
  const float4* pb4 = (const float4*)(P2 + (size_t)n*64*WW);
  int nx0 = min(c0+GR, WW-1) - max(c0-GR, 0) + 1;
  int nx1 = min(c1+GR, WW-1) - max(c1-GR, 0) + 1;
  const u32* ib2 = imgh2 + (size_t)n*3*HWSZ/2;
  float* ob = out + (size_t)n*3*HWSZ;

  int lo = y0-GR; if(lo < 0) lo = 0;
  int hi = y0+GR; if(hi > HH-1) hi = HH-1;
  int g_lo = lo >> 3;
  int g_hi = ((hi+1) >> 3) - 1;
  float sa0=0.f, sb0=0.f, sa1=0.f, sb1=0.f;
  #pragma unroll 6
  for(int g=g_lo; g<=g_hi; ++g){
    float4 v = pb4[(size_t)g*(WW/2) + t];
    sa0+=v.x; sb0+=v.y; sa1+=v.z; sb1+=v.w;
  }
  for(int y=(g_hi+1)*8; y<=hi; ++y){
    uint2 w = hb2[(size_t)y*(WW/2) + t];
    float2 va = unpack_h2(w.x), vb = unpack_h2(w.y);
    sa0+=va.x; sb0+=va.y; sa1+=vb.x; sb1+=vb.y;
  }

  #pragma unroll
  for(int g=0; g<2; ++g){
    uint2 ad[4], su[4];
    bool va4[4], vs4[4];
    #pragma unroll
    for(int j=0; j<4; ++j){
      int y = y0 + g*4 + j;
      int ya = y+GR+1, yr = y-GR;
      va4[j] = (ya < HH); vs4[j] = (yr >= 0);
      ad[j] = va4[j] ? hb2[(size_t)ya*(WW/2) + t] : make_uint2(0u,0u);
      su[j] = vs4[j] ? hb2[(size_t)yr*(WW/2) + t] : make_uint2(0u,0u);
    }
    #pragma unroll
    for(int j=0; j<4; ++j){
      int y = y0 + g*4 + j;
      int ny = min(y+GR, HH-1) - max(y-GR, 0) + 1;
      float rc0 = 1.f/(float)(nx0*ny);
      float rc1 = 1.f/(float)(nx1*ny);
      size_t ph = (size_t)y*(WW/2) + t;
      float2 i0 = unpack_h2(ib2[ph]);
      float2 i1 = unpack_h2(ib2[ph+HWSZ/2]);
      float2 i2 = unpack_h2(ib2[ph+HWSZ]);
      float g2a = (0.2989f*(2.f*i0.x-1.f) + 0.587f*(2.f*i1.x-1.f) + 0.114f*(2.f*i2.x-1.f) + 1.f)*0.5f;
      float g2b = (0.2989f*(2.f*i0.y-1.f) + 0.587f*(2.f*i1.y-1.f) + 0.114f*(2.f*i2.y-1.f) + 1.f)*0.5f;
      float rT0 = 1.0f / ((sa0*g2a + sb0)*rc0);
      float rT1 = 1.0f / ((sa1*g2b + sb1)*rc1);
      nt_store_f2((i0.x-A0)*rT0 + A0, (i0.y-A0)*rT1 + A0, &ob[2*ph]);
      nt_store_f2((i1.x-A1)*rT0 + A1, (i1.y-A1)*rT1 + A1, &ob[2*ph+HWSZ]);
      nt_store_f2((i2.x-A2)*rT0 + A2, (i2.y-A2)*rT1 + A2, &ob[2*ph+2*HWSZ]);
      if(va4[j]){ float2 va = unpack_h2(ad[j].x), vb = unpack_h2(ad[j].y); sa0+=va.x; sb0+=va.y; sa1+=vb.x; sb1+=vb.y; }
      if(vs4[j]){ float2 va = unpack_h2(su[j].x), vb = unpack_h2(su[j].y); sa0-=va.x; sb0-=va.y; sa1-=vb.x; sb1-=vb.y; }
    }
  }
}

extern "C" void kernel_launch(void* const* d_in, const int* in_sizes, int n_in,
                              void* d_out, int out_size, void* d_ws, size_t ws_size,
                              hipStream_t stream) {
  const float* x = (const float*)d_in[0];
  float* out = (float*)d_out;
  char* ws = (char*)d_ws;
  const size_t MB = 1u<<20;

  // region map (80.6 MiB + selection):
  u32*   imgh2 = (u32*)(ws + 0);            // 24 MiB packed f16 pairs, live whole pass
  u16*   guidh = (u16*)(ws + 24*MB);        //  8 MiB, prep -> hbox4
  // region A (32 MiB):
  float* rowm  = (float*)(ws + 32*MB);      // 16 MiB, prep -> cmhist
  float* dark  = (float*)(ws + 48*MB);      // 16 MiB, cmhist -> sel4
  uint2* h4    = (uint2*)(ws + 32*MB);      // 32 MiB, hbox4 -> vbox   (over rowm+dark)
  u32*   hab   = (u32*)(ws + 32*MB);        // 16 MiB, hbox2 -> final  (over h4)
  // region B (16 MiB):
  u16*   rowm2 = (u16*)(ws + 64*MB);        //  8 MiB, rowmin2 -> hbox4 (live!)
  float4* P4   = (float4*)(ws + 72*MB);     //  8 MiB, hbox4 -> vbox
  float2* P2   = (float2*)(ws + 64*MB);     //  4 MiB, hbox2 -> final (over rowm2, dead after hbox4)
  // ab scratch lives in d_out (overwritten by k_final, which doesn't read it)
  u32*   ab    = (u32*)out;                 // 16 MiB
  // selection state
  char* sm = ws + 80*MB;
  u32* hist1  = (u32*)sm;                             // 512 KiB
  u32* ties_i = (u32*)(sm + 512*1024);                // 768 KiB (16*12288*4)
  u32* ties_v = (u32*)(sm + 512*1024 + 768*1024);     // 768 KiB
  u32* st     = (u32*)(sm + 2048*1024);               // 1 KiB
  float* sums = (float*)(sm + 2048*1024 + 1024);
  float* Abuf = (float*)(sm + 2048*1024 + 1024 + 512);
  int zwords = (2048*1024 + 1024 + 512 + 512) / 4;

  // 1. prep (2 px/thread): img16 + guid16 + row-min + state zero
  k_prep<<<dim3(NIMG*HH), dim3(256), 0, stream>>>(x, imgh2, (u32*)guidh, (float2*)rowm, (u32*)sm, zwords);
  // 2. fused col-min dark + hist1
  k_cmhist<<<dim3(8, NIMG), dim3(1024), 0, stream>>>(rowm, dark, hist1);
  // 3. atmospheric light: sel4(+csel1, bin-level ties), sel5(exact two-phase)
  k_sel4<<<dim3(NIMG, 8), dim3(1024), 0, stream>>>(dark, x, hist1, st, sums, ties_i, ties_v);
  k_sel5<<<dim3(NIMG), dim3(1024), 0, stream>>>(x, st, sums, ties_i, ties_v, Abuf);
  // 4. transmission raw (2 px/thread row-min; col-min fused into hbox4)
  k_rowmin2<<<dim3(NIMG*HH), dim3(256), 0, stream>>>(imgh2, Abuf, (u32*)rowm2);
  // 5. guided filter round 1 (colmin_pT fused into hbox4 prologue)
  k_hbox4<<<dim3(NIMG*64), dim3(512), 0, stream>>>(guidh, rowm2, h4, P4);
  k_vbox_ab<<<dim3(2, HH/8, NIMG), dim3(256), 0, stream>>>(h4, P4, ab);
  // 6. guided filter round 2 -> T -> final output (2 px/thread)
  k_hbox2<<<dim3(NIMG*64), dim3(512), 0, stream>>>(ab, hab, P2);
  k_final<<<dim3(HH/8, NIMG), dim3(256), 0, stream>>>(hab, P2, imgh2, Abuf, out);
}

// Round 18
// 188.685 us; speedup vs baseline: 1.1327x; 1.0261x over previous
//
#include <hip/hip_runtime.h>
#include <hip/hip_fp16.h>

typedef unsigned int u32;
typedef unsigned short u16;
typedef unsigned long long u64;

#define NIMG 16
#define HH 512
#define WW 512
#define HWSZ (HH*WW)
#define TOPN 2621u
#define TIE_CAP 12288
#define GR 40

// ---------- f16 packing helpers ----------
static __device__ inline u16 f2h(float v){ __half h=__float2half_rn(v); return *reinterpret_cast<u16*>(&h); }
static __device__ inline float h2f(u16 v){ __half h=*reinterpret_cast<__half*>(&v); return __half2float(h); }
static __device__ inline uint2 pack_h4(float4 S){
  __half2 lo = __floats2half2_rn(S.x, S.y);
  __half2 hi = __floats2half2_rn(S.z, S.w);
  uint2 r;
  r.x = *reinterpret_cast<unsigned int*>(&lo);
  r.y = *reinterpret_cast<unsigned int*>(&hi);
  return r;
}
static __device__ inline float4 unpack_h4(uint2 v){
  __half2 lo = *reinterpret_cast<__half2*>(&v.x);
  __half2 hi = *reinterpret_cast<__half2*>(&v.y);
  float2 A = __half22float2(lo), B = __half22float2(hi);
  return make_float4(A.x, A.y, B.x, B.y);
}
static __device__ inline u32 pack_h2(float a, float b){
  __half2 h = __floats2half2_rn(a, b);
  return *reinterpret_cast<unsigned int*>(&h);
}
static __device__ inline float2 unpack_h2(u32 v){
  __half2 h = *reinterpret_cast<__half2*>(&v);
  return __half22float2(h);
}
static __device__ inline void nt_store_f2(float a, float b, float* p){
  float2 v = make_float2(a, b);
  __builtin_nontemporal_store(*reinterpret_cast<u64*>(&v), reinterpret_cast<u64*>(p));
}

// ------- prep (2 px/thread): x -> img16, guid16, row-min f32, zero state -------
__global__ void k_prep(const float* __restrict__ x, u32* __restrict__ imgh2,
                       u32* __restrict__ guidh2, float2* __restrict__ rowmo,
                       u32* __restrict__ state, int zwords){
  __shared__ float s[WW+14];
  int row = blockIdx.x; int n = row>>9; int y = row&511; int t = threadIdx.x;  // 256
  int zi = row*256 + t;
  if(zi < zwords) state[zi] = 0;
  const float2* xb = (const float2*)(x + (size_t)n*3*HWSZ + (size_t)y*WW);
  float2 x0 = xb[t], x1 = xb[t + HWSZ/2], x2 = xb[t + HWSZ];
  float i0a=(x0.x+1.f)*0.5f, i0b=(x0.y+1.f)*0.5f;
  float i1a=(x1.x+1.f)*0.5f, i1b=(x1.y+1.f)*0.5f;
  float i2a=(x2.x+1.f)*0.5f, i2b=(x2.y+1.f)*0.5f;
  size_t pb = ((size_t)n*3*HWSZ + (size_t)y*WW)/2 + t;
  imgh2[pb]          = pack_h2(i0a, i0b);
  imgh2[pb+HWSZ/2]   = pack_h2(i1a, i1b);
  imgh2[pb+HWSZ]     = pack_h2(i2a, i2b);
  float ga = (0.2989f*x0.x + 0.587f*x1.x + 0.114f*x2.x + 1.f)*0.5f;
  float gb = (0.2989f*x0.y + 0.587f*x1.y + 0.114f*x2.y + 1.f)*0.5f;
  size_t qb = ((size_t)n*HWSZ + (size_t)y*WW)/2 + t;
  guidh2[qb] = pack_h2(ga, gb);
  s[2*t+7] = fminf(i0a, fminf(i1a, i2a));
  s[2*t+8] = fminf(i0b, fminf(i1b, i2b));
  if(t < 7){ s[t] = 1.0f; s[WW+7+t] = 1.0f; }
  __syncthreads();
  float mm = s[2*t+1];
  #pragma unroll
  for(int d=2; d<15; ++d) mm = fminf(mm, s[2*t+d]);
  float v0 = fminf(s[2*t], mm);
  float v1 = fminf(mm, s[2*t+15]);
  rowmo[qb] = make_float2(v0, v1);
}

// ------- fused 15-tap col-min (dark, f32 exact) + hist1 -------
__global__ void k_cmhist(const float* __restrict__ rowm, float* __restrict__ dark,
                         u32* __restrict__ hist1){
  __shared__ u32 h[8192];
  int yg = blockIdx.x, n = blockIdx.y, t = threadIdx.x;
  for(int i=t; i<8192; i+=1024) h[i] = 0;
  int col = t & 511, sub = t >> 9;
  int rs = yg*64 + sub*32;                 // output rows rs..rs+31
  const float* rb = rowm + (size_t)n*HWSZ + col;
  float val[46];
  #pragma unroll
  for(int r=0; r<46; ++r){
    int yy = rs - 7 + r;
    val[r] = (yy >= 0 && yy < HH) ? rb[(size_t)yy*WW] : 1.0f;
  }
  __syncthreads();                          // LDS hist zeroed
  float* db = dark + (size_t)n*HWSZ + col;
  #pragma unroll
  for(int k=0; k<32; ++k){
    float m = val[k];
    #pragma unroll
    for(int d=1; d<15; ++d) m = fminf(m, val[k+d]);
    db[(size_t)(rs+k)*WW] = m;
    u32 key = __float_as_uint(m);
    int b = (int)(key >> 10) - 0xFC000;
    b = max(0, min(8191, b));
    atomicAdd(&h[b], 1u);
  }
  __syncthreads();
  u32* gh = hist1 + n*8192;
  for(int i=t; i<8192; i+=1024) if(h[i]) atomicAdd(&gh[i], h[i]);
}

__device__ inline u32 block_scan_incl(u32 v, int t, u32* wsum){
  #pragma unroll
  for(int d=1; d<64; d<<=1){
    u32 u = __shfl_up(v, d);
    if((t & 63) >= d) v += u;
  }
  if((t & 63) == 63) wsum[t >> 6] = v;
  __syncthreads();
  u32 carry = 0;
  for(int w=0; w < (t >> 6); ++w) carry += wsum[w];
  return v + carry;
}

// ------- sel4 with csel1 prologue; sums over bins > bin_hi, ties = whole bin_hi bin -------
__global__ void k_sel4(const float* __restrict__ dark, const float* __restrict__ x,
                       const u32* __restrict__ hist1, u32* __restrict__ st,
                       float* __restrict__ sums, u32* __restrict__ ties_i,
                       u32* __restrict__ ties_v){
  __shared__ u32 wsum[16];
  __shared__ u32 bc[1];
  __shared__ float red[1024];
  int n = blockIdx.x, part = blockIdx.y, t = threadIdx.x;   // 1024 threads
  const u32* hh = hist1 + n*8192;
  u32 loc[8]; u32 ps = 0;
  #pragma unroll
  for(int k=0; k<8; ++k){
    loc[k] = hh[8191 - (t*8 + k)];
    ps += loc[k];
  }
  u32 incl = block_scan_incl(ps, t, wsum);
  u32 excl = incl - ps;
  if(excl < TOPN && incl >= TOPN){
    u32 cum = excl;
    #pragma unroll
    for(int k=0; k<8; ++k){
      if(cum + loc[k] >= TOPN){
        bc[0] = (u32)(8191 - (t*8+k));
        st[n*16+6] = TOPN - cum;      // k_need (racing identical writes: benign)
        break;
      }
      cum += loc[k];
    }
  }
  __syncthreads();
  int bin_hi = (int)bc[0];
  const u32* d = (const u32*)(dark + (size_t)n*HWSZ);
  const float* xb = x + (size_t)n*3*HWSZ;
  float a0=0.f, a1=0.f, a2=0.f;
  int per = HWSZ/8, i0 = part*per;
  for(int i=i0+t; i<i0+per; i+=1024){
    u32 key = d[i];
    int b = (int)(key >> 10) - 0xFC000;
    b = max(0, min(8191, b));
    if(b > bin_hi){
      a0 += xb[i]; a1 += xb[i+HWSZ]; a2 += xb[i+2*HWSZ];
    } else if(b == bin_hi){
      u32 pos = atomicAdd(&st[n*16+7], 1u);
      if(pos < TIE_CAP){ ties_i[n*TIE_CAP + pos] = (u32)i; ties_v[n*TIE_CAP + pos] = key; }
    }
  }
  red[t]=a0; __syncthreads();
  for(int s=512;s>0;s>>=1){ if(t<s) red[t]+=red[t+s]; __syncthreads(); }
  if(t==0) atomicAdd(&sums[n*8+0], red[0]);
  __syncthreads();
  red[t]=a1; __syncthreads();
  for(int s=512;s>0;s>>=1){ if(t<s) red[t]+=red[t+s]; __syncthreads(); }
  if(t==0) atomicAdd(&sums[n*8+1], red[0]);
  __syncthreads();
  red[t]=a2; __syncthreads();
  for(int s=512;s>0;s>>=1){ if(t<s) red[t]+=red[t+s]; __syncthreads(); }
  if(t==0) atomicAdd(&sums[n*8+2], red[0]);
}

// ---- sel5: exact top-k among bin ties: low-10-bit value search, then index cutoff ----
__global__ void k_sel5(const float* __restrict__ x, const u32* __restrict__ st,
                       const float* __restrict__ sums, const u32* __restrict__ ties_i,
                       const u32* __restrict__ ties_v, float* __restrict__ A){
  __shared__ u32 tl[TIE_CAP];
  __shared__ u16 kv[TIE_CAP];
  __shared__ u32 redu[1024];
  __shared__ float red[1024];
  __shared__ float fin[3];
  int n = blockIdx.x, t = threadIdx.x;   // 1024
  u32 k_need = st[n*16+6];
  u32 m = st[n*16+7]; if(m > TIE_CAP) m = TIE_CAP;
  const float* xb = x + (size_t)n*3*HWSZ;
  for(u32 e=t; e<m; e+=1024){
    tl[e] = ties_i[n*TIE_CAP + e];
    kv[e] = (u16)(ties_v[n*TIE_CAP + e] & 1023u);
  }
  __syncthreads();
  u32 vlo = 0u, vhi = 1023u;
  while(vlo < vhi){
    u32 mid = (vlo + vhi + 1u) >> 1;
    u32 c = 0;
    for(u32 e=t; e<m; e+=1024) c += ((u32)kv[e] >= mid) ? 1u : 0u;
    redu[t] = c; __syncthreads();
    for(int s=512;s>0;s>>=1){ if(t<s) redu[t]+=redu[t+s]; __syncthreads(); }
    u32 total = redu[0]; __syncthreads();
    if(total >= k_need) vlo = mid; else vhi = mid - 1u;
  }
  u32 vstar = vlo;
  {
    u32 c = 0;
    for(u32 e=t; e<m; e+=1024) c += ((u32)kv[e] > vstar) ? 1u : 0u;
    redu[t] = c; __syncthreads();
    for(int s=512;s>0;s>>=1){ if(t<s) redu[t]+=redu[t+s]; __syncthreads(); }
  }
  u32 cnt_gt = redu[0]; __syncthreads();
  u32 k2 = k_need - cnt_gt;
  u32 lo = 0, hi = HWSZ;
  while(lo < hi){
    u32 mid = (lo + hi) >> 1;
    u32 c = 0;
    for(u32 e=t; e<m; e+=1024) c += ((u32)kv[e] == vstar && tl[e] < mid) ? 1u : 0u;
    redu[t] = c; __syncthreads();
    for(int s=512;s>0;s>>=1){ if(t<s) redu[t]+=redu[t+s]; __syncthreads(); }
    u32 total = redu[0]; __syncthreads();
    if(total >= k2) hi = mid; else lo = mid + 1;
  }
  u32 C = lo;
  float a0=0.f, a1=0.f, a2=0.f;
  for(u32 e=t; e<m; e+=1024){
    u32 idx = tl[e];
    bool sel = ((u32)kv[e] > vstar) || ((u32)kv[e] == vstar && idx < C);
    if(sel){ a0 += xb[idx]; a1 += xb[idx+HWSZ]; a2 += xb[idx+2*HWSZ]; }
  }
  red[t]=a0; __syncthreads();
  for(int s=512;s>0;s>>=1){ if(t<s) red[t]+=red[t+s]; __syncthreads(); }
  if(t==0) fin[0]=red[0];
  __syncthreads();
  red[t]=a1; __syncthreads();
  for(int s=512;s>0;s>>=1){ if(t<s) red[t]+=red[t+s]; __syncthreads(); }
  if(t==0) fin[1]=red[0];
  __syncthreads();
  red[t]=a2; __syncthreads();
  for(int s=512;s>0;s>>=1){ if(t<s) red[t]+=red[t+s]; __syncthreads(); }
  if(t==0){
    fin[2]=red[0];
    for(int c=0;c<3;++c){
      float tot = sums[n*8+c] + fin[c];
      float Ac = (tot / 2621.0f + 1.0f) * 0.5f;
      A[n*8+c]   = Ac;
      A[n*8+4+c] = 1.0f / Ac;
    }
  }
}

// ---------------- rowmin of img/A, 2 px/thread (packed u32 in/out) ----------------
__global__ void k_rowmin2(const u32* __restrict__ imgh2, const float* __restrict__ A,
                          u32* __restrict__ rowm2){
  __shared__ float s[WW+14];
  int row = blockIdx.x; int n = row>>9; int y = row&511; int t = threadIdx.x;  // 256
  float ia0=A[n*8+4], ia1=A[n*8+5], ia2=A[n*8+6];
  size_t pb = ((size_t)n*3*HWSZ + (size_t)y*WW)/2 + t;
  float2 i0 = unpack_h2(imgh2[pb]);
  float2 i1 = unpack_h2(imgh2[pb+HWSZ/2]);
  float2 i2 = unpack_h2(imgh2[pb+HWSZ]);
  s[2*t+7] = fminf(i0.x*ia0, fminf(i1.x*ia1, i2.x*ia2));
  s[2*t+8] = fminf(i0.y*ia0, fminf(i1.y*ia1, i2.y*ia2));
  if(t < 7){ s[t] = 1.0f; s[WW+7+t] = 1.0f; }
  __syncthreads();
  float mm = s[2*t+1];
  #pragma unroll
  for(int d=2; d<15; ++d) mm = fminf(mm, s[2*t+d]);
  float v0 = fminf(s[2*t], mm);
  float v1 = fminf(mm, s[2*t+15]);
  rowm2[((size_t)n*HWSZ + (size_t)y*WW)/2 + t] = pack_h2(v0, v1);
}

// -------- hbox4 with fused col-min prologue (reads rowm2) + horizontal box sums + P4 --------
__global__ void k_hbox4(const u16* __restrict__ guidh, const u16* __restrict__ rowm2,
                        uint2* __restrict__ h4, float4* __restrict__ P4){
  __shared__ float4 wsum[8];
  __shared__ float4 pref[WW];
  int b = blockIdx.x; int n = b >> 6; int g = b & 63; int t = threadIdx.x;
  int lane = t & 63, wv = t >> 6;
  const u16* rb = rowm2 + (size_t)n*HWSZ;
  float val[22];
  #pragma unroll
  for(int r=0; r<22; ++r){
    int yy = g*8 - 7 + r;
    val[r] = (yy >= 0 && yy < HH) ? h2f(rb[(size_t)yy*WW + t]) : 1.0f;
  }
  float Pv[8];
  #pragma unroll
  for(int j=0; j<8; ++j){
    float mn = val[j];
    #pragma unroll
    for(int d=1; d<15; ++d) mn = fminf(mn, val[j+d]);
    Pv[j] = h2f(f2h(1.0f - 0.95f*mn));   // replicate f16 round-trip exactly
  }
  float4 psum = {0.f,0.f,0.f,0.f};
  for(int j=0; j<8; ++j){
    int y = g*8 + j;
    size_t off = (size_t)n*HWSZ + (size_t)y*WW + t;
    float I = h2f(guidh[off]);
    float P = Pv[j];
    float4 s; s.x = I; s.y = P; s.z = I*P; s.w = I*I;
    #pragma unroll
    for(int d=1; d<64; d<<=1){
      float ux=__shfl_up(s.x,d), uy=__shfl_up(s.y,d), uz=__shfl_up(s.z,d), uw=__shfl_up(s.w,d);
      if(lane >= d){ s.x+=ux; s.y+=uy; s.z+=uz; s.w+=uw; }
    }
    if(lane == 63) wsum[wv] = s;
    __syncthreads();
    float4 c = {0.f,0.f,0.f,0.f};
    for(int w=0; w<wv; ++w){ float4 q=wsum[w]; c.x+=q.x; c.y+=q.y; c.z+=q.z; c.w+=q.w; }
    s.x+=c.x; s.y+=c.y; s.z+=c.z; s.w+=c.w;
    pref[t] = s;
    __syncthreads();
    int hi = min(t+GR, WW-1);
    float4 S = pref[hi];
    if(t >= GR+1){ float4 L = pref[t-GR-1]; S.x-=L.x; S.y-=L.y; S.z-=L.z; S.w-=L.w; }
    uint2 pk = pack_h4(S);
    h4[off] = pk;
    float4 r = unpack_h4(pk);     // accumulate ROUNDED values
    psum.x+=r.x; psum.y+=r.y; psum.z+=r.z; psum.w+=r.w;
    __syncthreads();
  }
  P4[((size_t)n*64 + g)*WW + t] = psum;
}

// ---- fused vertical running box (pyramid init) -> (a,b) -> horizontal box -> hab, P2 ----
// block: image n, 8 rows; 512 threads (full row). Same per-row sync structure as k_hbox2.
__global__ void k_vbox2(const uint2* __restrict__ h4, const float4* __restrict__ P4,
                        u32* __restrict__ hab, float2* __restrict__ P2){
  __shared__ float2 wsum2[8];
  __shared__ float2 pref2[WW];
  int b = blockIdx.x; int n = b >> 6; int g = b & 63; int t = threadIdx.x;  // 512
  int y0 = g*8;
  const uint2* hb = h4 + (size_t)n*HWSZ;
  const float4* pb = P4 + (size_t)n*64*WW + t;
  u32* habb = hab + (size_t)n*HWSZ;
  int nx = min(t+GR, WW-1) - max(t-GR, 0) + 1;

  int lo = y0-GR; if(lo < 0) lo = 0;
  int hi = y0+GR; if(hi > HH-1) hi = HH-1;
  int g_lo = lo >> 3;
  int g_hi = ((hi+1) >> 3) - 1;
  float s0=0.f, s1=0.f, s2=0.f, s3=0.f;
  #pragma unroll 6
  for(int gg=g_lo; gg<=g_hi; ++gg){
    float4 v = pb[(size_t)gg*WW];
    s0+=v.x; s1+=v.y; s2+=v.z; s3+=v.w;
  }
  for(int y=(g_hi+1)*8; y<=hi; ++y){
    float4 v = unpack_h4(hb[(size_t)y*WW + t]);
    s0+=v.x; s1+=v.y; s2+=v.z; s3+=v.w;
  }

  int lane = t & 63, wv = t >> 6;
  float2 psum = {0.f,0.f};
  for(int j=0; j<8; ++j){
    int y = y0 + j;
    int ny = min(y+GR, HH-1) - max(y-GR, 0) + 1;
    float rc = 1.f/(float)(nx*ny);
    float mI=s0*rc, mP=s1*rc, mIp=s2*rc, mII=s3*rc;
    float va = (mIp - mI*mP) / (mII - mI*mI + 1e-3f);
    float vb = mP - va*mI;
    float2 s = unpack_h2(pack_h2(va, vb));    // rounded ab: replicate old f16 round-trip
    #pragma unroll
    for(int d=1; d<64; d<<=1){
      float ux=__shfl_up(s.x,d), uy=__shfl_up(s.y,d);
      if(lane >= d){ s.x+=ux; s.y+=uy; }
    }
    if(lane == 63) wsum2[wv] = s;
    __syncthreads();
    float2 c = {0.f,0.f};
    for(int w=0; w<wv; ++w){ float2 q=wsum2[w]; c.x+=q.x; c.y+=q.y; }
    s.x+=c.x; s.y+=c.y;
    pref2[t] = s;
    __syncthreads();
    int hx = min(t+GR, WW-1);
    float2 S = pref2[hx];
    if(t >= GR+1){ float2 L = pref2[t-GR-1]; S.x-=L.x; S.y-=L.y; }
    u32 pk = pack_h2(S.x, S.y);
    habb[(size_t)y*WW + t] = pk;
    float2 rr = unpack_h2(pk);
    psum.x+=rr.x; psum.y+=rr.y;
    __syncthreads();
    // vertical window update for next row
    int ya = y+GR+1, yr = y-GR;
    if(ya < HH){ float4 v = unpack_h4(hb[(size_t)ya*WW + t]); s0+=v.x; s1+=v.y; s2+=v.z; s3+=v.w; }
    if(yr >= 0){ float4 v = unpack_h4(hb[(size_t)yr*WW + t]); s0-=v.x; s1-=v.y; s2-=v.z; s3-=v.w; }
  }
  P2[((size_t)n*64 + g)*WW + t] = psum;
}

// ------- final, 2 px/thread: vertical sums of (a,b) + pyramid -> T -> composite -------
__global__ void k_final(const u32* __restrict__ hab, const float2* __restrict__ P2,
                        const u32* __restrict__ imgh2,
                        const float* __restrict__ A, float* __restrict__ out){
  int t = threadIdx.x;            // 256: column pair (2t, 2t+1)
  int y0 = blockIdx.x*8;
  int n = blockIdx.y;
  int c0 = 2*t, c1 = 2*t+1;
  float A0=A[n*8+0], A1=A[n*8+1], A2=A[n*8+2];
  const uint2* hb2 = (const uint2*)(hab + (size_t)n*HWSZ);
  const float4* pb4 = (const float4*)(P2 + (size_t)n*64*WW);
  int nx0 = min(c0+GR, WW-1) - max(c0-GR, 0) + 1;
  int nx1 = min(c1+GR, WW-1) - max(c1-GR, 0) + 1;
  const u32* ib2 = imgh2 + (size_t)n*3*HWSZ/2;
  float* ob = out + (size_t)n*3*HWSZ;

  int lo = y0-GR; if(lo < 0) lo = 0;
  int hi = y0+GR; if(hi > HH-1) hi = HH-1;
  int g_lo = lo >> 3;
  int g_hi = ((hi+1) >> 3) - 1;
  float sa0=0.f, sb0=0.f, sa1=0.f, sb1=0.f;
  #pragma unroll 6
  for(int g=g_lo; g<=g_hi; ++g){
    float4 v = pb4[(size_t)g*(WW/2) + t];
    sa0+=v.x; sb0+=v.y; sa1+=v.z; sb1+=v.w;
  }
  for(int y=(g_hi+1)*8; y<=hi; ++y){
    uint2 w = hb2[(size_t)y*(WW/2) + t];
    float2 va = unpack_h2(w.x), vb = unpack_h2(w.y);
    sa0+=va.x; sb0+=va.y; sa1+=vb.x; sb1+=vb.y;
  }

  #pragma unroll
  for(int g=0; g<2; ++g){
    uint2 ad[4], su[4];
    bool va4[4], vs4[4];
    #pragma unroll
    for(int j=0; j<4; ++j){
      int y = y0 + g*4 + j;
      int ya = y+GR+1, yr = y-GR;
      va4[j] = (ya < HH); vs4[j] = (yr >= 0);
      ad[j] = va4[j] ? hb2[(size_t)ya*(WW/2) + t] : make_uint2(0u,0u);
      su[j] = vs4[j] ? hb2[(size_t)yr*(WW/2) + t] : make_uint2(0u,0u);
    }
    #pragma unroll
    for(int j=0; j<4; ++j){
      int y = y0 + g*4 + j;
      int ny = min(y+GR, HH-1) - max(y-GR, 0) + 1;
      float rc0 = 1.f/(float)(nx0*ny);
      float rc1 = 1.f/(float)(nx1*ny);
      size_t ph = (size_t)y*(WW/2) + t;
      float2 i0 = unpack_h2(ib2[ph]);
      float2 i1 = unpack_h2(ib2[ph+HWSZ/2]);
      float2 i2 = unpack_h2(ib2[ph+HWSZ]);
      float g2a = (0.2989f*(2.f*i0.x-1.f) + 0.587f*(2.f*i1.x-1.f) + 0.114f*(2.f*i2.x-1.f) + 1.f)*0.5f;
      float g2b = (0.2989f*(2.f*i0.y-1.f) + 0.587f*(2.f*i1.y-1.f) + 0.114f*(2.f*i2.y-1.f) + 1.f)*0.5f;
      float rT0 = 1.0f / ((sa0*g2a + sb0)*rc0);
      float rT1 = 1.0f / ((sa1*g2b + sb1)*rc1);
      nt_store_f2((i0.x-A0)*rT0 + A0, (i0.y-A0)*rT1 + A0, &ob[2*ph]);
      nt_store_f2((i1.x-A1)*rT0 + A1, (i1.y-A1)*rT1 + A1, &ob[2*ph+HWSZ]);
      nt_store_f2((i2.x-A2)*rT0 + A2, (i2.y-A2)*rT1 + A2, &ob[2*ph+2*HWSZ]);
      if(va4[j]){ float2 va = unpack_h2(ad[j].x), vb = unpack_h2(ad[j].y); sa0+=va.x; sb0+=va.y; sa1+=vb.x; sb1+=vb.y; }
      if(vs4[j]){ float2 va = unpack_h2(su[j].x), vb = unpack_h2(su[j].y); sa0-=va.x; sb0-=va.y; sa1-=vb.x; sb1-=vb.y; }
    }
  }
}

extern "C" void kernel_launch(void* const* d_in, const int* in_sizes, int n_in,
                              void* d_out, int out_size, void* d_ws, size_t ws_size,
                              hipStream_t stream) {
  const float* x = (const float*)d_in[0];
  float* out = (float*)d_out;
  char* ws = (char*)d_ws;
  const size_t MB = 1u<<20;

  // region map (80.6 MiB + selection):
  u32*   imgh2 = (u32*)(ws + 0);            // 24 MiB packed f16 pairs, live whole pass
  u16*   guidh = (u16*)(ws + 24*MB);        //  8 MiB, prep -> hbox4
  // region A (32 MiB):
  float* rowm  = (float*)(ws + 32*MB);      // 16 MiB, prep -> cmhist
  float* dark  = (float*)(ws + 48*MB);      // 16 MiB, cmhist -> sel4
  uint2* h4    = (uint2*)(ws + 32*MB);      // 32 MiB, hbox4 -> vbox2  (over rowm+dark)
  // region B (16 MiB):
  u16*   rowm2 = (u16*)(ws + 64*MB);        //  8 MiB, rowmin2 -> hbox4 (live!)
  float4* P4   = (float4*)(ws + 72*MB);     //  8 MiB, hbox4 -> vbox2
  float2* P2   = (float2*)(ws + 64*MB);     //  4 MiB, vbox2 -> final (over rowm2, dead after hbox4)
  // hab lives in d_out scratch region (overwritten by k_final, which reads it only via hb2 before writing)
  u32*   hab   = (u32*)(ws + 80*MB);        // 16 MiB, vbox2 -> final
  // selection state
  char* sm = ws + 96*MB;
  u32* hist1  = (u32*)sm;                             // 512 KiB
  u32* ties_i = (u32*)(sm + 512*1024);                // 768 KiB (16*12288*4)
  u32* ties_v = (u32*)(sm + 512*1024 + 768*1024);     // 768 KiB
  u32* st     = (u32*)(sm + 2048*1024);               // 1 KiB
  float* sums = (float*)(sm + 2048*1024 + 1024);
  float* Abuf = (float*)(sm + 2048*1024 + 1024 + 512);
  int zwords = (2048*1024 + 1024 + 512 + 512) / 4;

  // 1. prep (2 px/thread): img16 + guid16 + row-min + state zero
  k_prep<<<dim3(NIMG*HH), dim3(256), 0, stream>>>(x, imgh2, (u32*)guidh, (float2*)rowm, (u32*)sm, zwords);
  // 2. fused col-min dark + hist1
  k_cmhist<<<dim3(8, NIMG), dim3(1024), 0, stream>>>(rowm, dark, hist1);
  // 3. atmospheric light: sel4(+csel1, bin-level ties), sel5(exact two-phase)
  k_sel4<<<dim3(NIMG, 8), dim3(1024), 0, stream>>>(dark, x, hist1, st, sums, ties_i, ties_v);
  k_sel5<<<dim3(NIMG), dim3(1024), 0, stream>>>(x, st, sums, ties_i, ties_v, Abuf);
  // 4. transmission raw (2 px/thread row-min; col-min fused into hbox4)
  k_rowmin2<<<dim3(NIMG*HH), dim3(256), 0, stream>>>(imgh2, Abuf, (u32*)rowm2);
  // 5. guided filter round 1 (colmin_pT fused into hbox4 prologue)
  k_hbox4<<<dim3(NIMG*64), dim3(512), 0, stream>>>(guidh, rowm2, h4, P4);
  // 6. guided filter round 2 fused: vertical box -> (a,b) -> horizontal box -> hab,P2
  k_vbox2<<<dim3(NIMG*64), dim3(512), 0, stream>>>(h4, P4, hab, P2);
  // 7. final composite (2 px/thread)
  k_final<<<dim3(HH/8, NIMG), dim3(256), 0, stream>>>(hab, P2, imgh2, Abuf, out);
}